// Round 5
// baseline (1600.695 us; speedup 1.0000x reference)
//
#include <hip/hip_runtime.h>
#include <hip/hip_bf16.h>
#include <math.h>

#define NHEAD 12
#define CDIM 384
#define QKVC 1152
#define MLPH 1536
#define SCALE 0.17677669529663687f  // 32^-0.5

typedef __attribute__((ext_vector_type(8))) short short8;
typedef __attribute__((ext_vector_type(4))) float f32x4;

static __device__ __forceinline__ unsigned short f2bf(float f) {
  union { __hip_bfloat16 b; unsigned short u; } c;
  c.b = __float2bfloat16(f);
  return c.u;
}

// ---------------- LN (wave per token, C=384) -> bf16 out ----------------
__global__ void ln_kernel(const float* __restrict__ X, const float* __restrict__ g,
                          const float* __restrict__ b, __hip_bfloat16* __restrict__ Y, int T) {
  int wid = (blockIdx.x * blockDim.x + threadIdx.x) >> 6;
  int lane = threadIdx.x & 63;
  if (wid >= T) return;
  const float* x = X + (size_t)wid * CDIM;
  float vals[6];
  float s = 0.f;
#pragma unroll
  for (int i = 0; i < 6; i++) { vals[i] = x[lane + i * 64]; s += vals[i]; }
#pragma unroll
  for (int o = 32; o > 0; o >>= 1) s += __shfl_xor(s, o);
  float m = s * (1.f / 384.f);
  float vs = 0.f;
#pragma unroll
  for (int i = 0; i < 6; i++) { float d = vals[i] - m; vs += d * d; }
#pragma unroll
  for (int o = 32; o > 0; o >>= 1) vs += __shfl_xor(vs, o);
  float rs = rsqrtf(vs * (1.f / 384.f) + 1e-5f);
  __hip_bfloat16* y = Y + (size_t)wid * CDIM;
#pragma unroll
  for (int i = 0; i < 6; i++) {
    int c = lane + i * 64;
    y[c] = __float2bfloat16((vals[i] - m) * rs * g[c] + b[c]);
  }
}

// ------------- qkv of a padded (zero) token: ln1_b @ qkv_w + qkv_b -> bf16 -------------
__global__ void pad_qkv_kernel(const float* __restrict__ lb, const float* __restrict__ Wq,
                               const float* __restrict__ bq, __hip_bfloat16* __restrict__ outp) {
  int j = blockIdx.x * blockDim.x + threadIdx.x;
  if (j >= QKVC) return;
  float s = bq[j];
  for (int c = 0; c < CDIM; c++) s += lb[c] * Wq[(size_t)c * QKVC + j];
  outp[j] = __float2bfloat16(s);
}

// ------------- expand relative-position bias to padded [12][64][64] f32 -------------
__global__ void expand_bias(const float* __restrict__ biases, const int* __restrict__ bidx,
                            float* __restrict__ Bexp, int n_off) {
  int h = blockIdx.x;
  for (int e = threadIdx.x; e < 4096; e += 256) {
    int n = e >> 6, m = e & 63;
    float v;
    if (m >= 49) v = -1e30f;
    else if (n >= 49) v = 0.f;
    else v = biases[h * n_off + bidx[n * 49 + m]];
    Bexp[h * 4096 + e] = v;
  }
}

// ---------------- weight transpose + f32->bf16 convert: W[K][N] -> Wt[N][K] ----------------
__global__ void wt_convert(const float* __restrict__ W, __hip_bfloat16* __restrict__ Wt,
                           int K, int N) {
  __shared__ float t[32][33];
  int n0 = blockIdx.x * 32, k0 = blockIdx.y * 32;
  int tx = threadIdx.x, ty = threadIdx.y;  // 32 x 8
#pragma unroll
  for (int i = 0; i < 4; i++) t[ty + i * 8][tx] = W[(size_t)(k0 + ty + i * 8) * N + n0 + tx];
  __syncthreads();
#pragma unroll
  for (int i = 0; i < 4; i++)
    Wt[(size_t)(n0 + ty + i * 8) * K + k0 + tx] = __float2bfloat16(t[tx][ty + i * 8]);
}

// ---------------- bf16 MFMA GEMM, 128x128 tile + XCD-chunked swizzle ----------------
// A: M x K bf16 row-major. Bt: N x K bf16 row-major. 1-D grid of gx*(M/128) blocks.
// Swizzle keeps all n-tiles of an M-panel on one XCD so the A panel stays in its L2.
template <int GELU, int HAS_RES, int OUT_BF16>
__global__ __launch_bounds__(256) void gemm_mfma(
    const __hip_bfloat16* __restrict__ A, const __hip_bfloat16* __restrict__ Bt,
    const float* __restrict__ bias, const float* __restrict__ res,
    void* __restrict__ Cout, int M, int N, int K, int gx) {
  __shared__ unsigned short Al[128][72];
  __shared__ unsigned short Bl[128][72];
  int T = gridDim.x;
  int f = blockIdx.x;
  int t = (f & 7) * (T >> 3) + (f >> 3);  // T % 8 == 0 always (M/128 multiple of 8)
  int n0 = (t % gx) * 128, m0 = (t / gx) * 128;
  int tid = threadIdx.x;
  int wave = tid >> 6, lane = tid & 63;
  int wm = (wave >> 1) * 64, wn = (wave & 1) * 64;
  int l15 = lane & 15, l4 = lane >> 4;

  int row = tid >> 1, cg = (tid & 1) * 32;  // 32 bf16 per thread per tile
  const __hip_bfloat16* Ag = A + (size_t)(m0 + row) * K + cg;
  const __hip_bfloat16* Bg = Bt + (size_t)(n0 + row) * K + cg;

  f32x4 acc[4][4] = {};

  for (int kt = 0; kt < K; kt += 64) {
    uint4 av[4], bv[4];
#pragma unroll
    for (int i = 0; i < 4; i++) {
      av[i] = *(const uint4*)(Ag + kt + i * 8);
      bv[i] = *(const uint4*)(Bg + kt + i * 8);
    }
    __syncthreads();
#pragma unroll
    for (int i = 0; i < 4; i++) {
      *(uint4*)&Al[row][cg + i * 8] = av[i];
      *(uint4*)&Bl[row][cg + i * 8] = bv[i];
    }
    __syncthreads();
#pragma unroll
    for (int kk = 0; kk < 64; kk += 32) {
      short8 af[4], bfr[4];
#pragma unroll
      for (int i = 0; i < 4; i++)
        af[i] = *(const short8*)&Al[wm + i * 16 + l15][kk + l4 * 8];
#pragma unroll
      for (int j = 0; j < 4; j++)
        bfr[j] = *(const short8*)&Bl[wn + j * 16 + l15][kk + l4 * 8];
#pragma unroll
      for (int i = 0; i < 4; i++)
#pragma unroll
        for (int j = 0; j < 4; j++)
          acc[i][j] = __builtin_amdgcn_mfma_f32_16x16x32_bf16(af[i], bfr[j], acc[i][j], 0, 0, 0);
    }
  }

#pragma unroll
  for (int i = 0; i < 4; i++) {
#pragma unroll
    for (int j = 0; j < 4; j++) {
      int n = n0 + wn + j * 16 + l15;
      float bv = bias[n];
#pragma unroll
      for (int r = 0; r < 4; r++) {
        int m = m0 + wm + i * 16 + l4 * 4 + r;
        float c = acc[i][j][r] + bv;
        if (GELU) c = 0.5f * c * (1.f + erff(c * 0.70710678118654752f));
        if (HAS_RES) c += res[(size_t)m * N + n];
        if (OUT_BF16)
          ((__hip_bfloat16*)Cout)[(size_t)m * N + n] = __float2bfloat16(c);
        else
          ((float*)Cout)[(size_t)m * N + n] = c;
      }
    }
  }
}

// ---------------- MFMA window attention: 1 wave per (window, head) ----------------
__global__ __launch_bounds__(64) void attn_mfma(
    const __hip_bfloat16* __restrict__ qkv, const __hip_bfloat16* __restrict__ qkv_pad,
    const float* __restrict__ Bexp, __hip_bfloat16* __restrict__ aw) {
  int h = blockIdx.x % NHEAD;
  int w = blockIdx.x / NHEAD;
  int b = w / 25, wi = w % 25;
  int wh = wi / 5, wv = wi % 5;

  __shared__ unsigned short Q[64][40];
  __shared__ unsigned short K[64][40];
  __shared__ unsigned short Vt[32][72];
  __shared__ unsigned short P[64][72];

  int lane = threadIdx.x;
  int l15 = lane & 15, l4 = lane >> 4;

  {
    int t = lane;
    uint4 z = {0, 0, 0, 0};
    uint4 qv[4], kv[4];
    union { uint4 u[4]; unsigned short s[32]; } vu;
    bool use = t < 49;
    const unsigned short* src = (const unsigned short*)qkv_pad + h * 96;
    if (use) {
      int hh = wh * 7 + t / 7, ww = wv * 7 + t % 7;
      if (hh < 32 && ww < 32)
        src = (const unsigned short*)qkv + (size_t)(b * 1024 + hh * 32 + ww) * QKVC + h * 96;
    }
#pragma unroll
    for (int c = 0; c < 4; c++) {
      qv[c]   = use ? *(const uint4*)(src + c * 8)      : z;
      kv[c]   = use ? *(const uint4*)(src + 32 + c * 8) : z;
      vu.u[c] = use ? *(const uint4*)(src + 64 + c * 8) : z;
    }
#pragma unroll
    for (int c = 0; c < 4; c++) {
      *(uint4*)&Q[t][c * 8] = qv[c];
      *(uint4*)&K[t][c * 8] = kv[c];
    }
#pragma unroll
    for (int d = 0; d < 32; d++) Vt[d][t] = vu.s[d];
  }
  __syncthreads();

  f32x4 acc[4][4] = {};
  {
    short8 aq[4], bk[4];
#pragma unroll
    for (int i = 0; i < 4; i++) aq[i] = *(const short8*)&Q[i * 16 + l15][l4 * 8];
#pragma unroll
    for (int j = 0; j < 4; j++) bk[j] = *(const short8*)&K[j * 16 + l15][l4 * 8];
#pragma unroll
    for (int i = 0; i < 4; i++)
#pragma unroll
      for (int j = 0; j < 4; j++)
        acc[i][j] = __builtin_amdgcn_mfma_f32_16x16x32_bf16(aq[i], bk[j], acc[i][j], 0, 0, 0);
  }

  const float* Bh = Bexp + h * 4096;
  float rinv_[4][4];
#pragma unroll
  for (int i = 0; i < 4; i++) {
    float s[4][4];
#pragma unroll
    for (int j = 0; j < 4; j++)
#pragma unroll
      for (int r = 0; r < 4; r++) {
        int n = i * 16 + l4 * 4 + r, m = j * 16 + l15;
        s[j][r] = acc[i][j][r] * SCALE + Bh[n * 64 + m];
      }
#pragma unroll
    for (int r = 0; r < 4; r++) {
      float mx = fmaxf(fmaxf(s[0][r], s[1][r]), fmaxf(s[2][r], s[3][r]));
#pragma unroll
      for (int o = 1; o < 16; o <<= 1) mx = fmaxf(mx, __shfl_xor(mx, o));
      float p[4], sm = 0.f;
#pragma unroll
      for (int j = 0; j < 4; j++) { p[j] = __expf(s[j][r] - mx); sm += p[j]; }
#pragma unroll
      for (int o = 1; o < 16; o <<= 1) sm += __shfl_xor(sm, o);
      rinv_[i][r] = 1.f / sm;
      int n = i * 16 + l4 * 4 + r;
#pragma unroll
      for (int j = 0; j < 4; j++) P[n][j * 16 + l15] = f2bf(p[j]);
    }
  }
  __syncthreads();

  f32x4 o[4][2] = {};
#pragma unroll
  for (int ks = 0; ks < 2; ks++) {
    short8 pa[4], vb[2];
#pragma unroll
    for (int i = 0; i < 4; i++) pa[i] = *(const short8*)&P[i * 16 + l15][ks * 32 + l4 * 8];
#pragma unroll
    for (int j = 0; j < 2; j++) vb[j] = *(const short8*)&Vt[j * 16 + l15][ks * 32 + l4 * 8];
#pragma unroll
    for (int i = 0; i < 4; i++)
#pragma unroll
      for (int j = 0; j < 2; j++)
        o[i][j] = __builtin_amdgcn_mfma_f32_16x16x32_bf16(pa[i], vb[j], o[i][j], 0, 0, 0);
  }

#pragma unroll
  for (int i = 0; i < 4; i++)
#pragma unroll
    for (int r = 0; r < 4; r++) {
      int n = i * 16 + l4 * 4 + r;
      if (n < 49) {
        int hh = wh * 7 + n / 7, ww = wv * 7 + n % 7;
        if (hh < 32 && ww < 32) {
          __hip_bfloat16* dst = aw + (size_t)(b * 1024 + hh * 32 + ww) * CDIM + h * 32;
          float ri = rinv_[i][r];
#pragma unroll
          for (int j = 0; j < 2; j++)
            dst[j * 16 + l15] = __float2bfloat16(o[i][j][r] * ri);
        }
      }
    }
}

// ------- fused depthwise 3x3 conv + BN + LN2: block = (b, x, y-half), thread = channel -------
__global__ __launch_bounds__(384) void conv_bn_ln_kernel(
    const float* __restrict__ X, const float* __restrict__ W9,
    const float* __restrict__ g, const float* __restrict__ bb,
    const float* __restrict__ mm, const float* __restrict__ vv,
    const float* __restrict__ lg, const float* __restrict__ lb,
    float* __restrict__ X2, __hip_bfloat16* __restrict__ XN) {
  int nwg = gridDim.x;
  int id = blockIdx.x;
  int nid = (id & 7) * (nwg >> 3) + (id >> 3);
  int yh = nid & 1;
  int x = (nid >> 1) & 31;
  int b = nid >> 6;
  int c = threadIdx.x;

  float w[9];
#pragma unroll
  for (int i = 0; i < 9; i++) w[i] = W9[c * 9 + i];
  float bnsc = rsqrtf(vv[c] + 1e-5f) * g[c];
  float bnsh = bb[c] - mm[c] * bnsc;
  float lgc = lg[c], lbc = lb[c];

  bool xm = x > 0, xp = x < 31;
  const float* colbase = X + ((size_t)(b * 1024 + x)) * CDIM + c;

  __shared__ float part[2][6][2];
  int wv = threadIdx.x >> 6, ln = threadIdx.x & 63;

  float w0[3], w1[3], w2[3];
  int y0 = yh * 16;
  if (y0 == 0) {
    w0[0] = w0[1] = w0[2] = 0.f;
  } else {
    const float* p = colbase + (size_t)(y0 - 1) * 32 * CDIM;
    w0[0] = xm ? p[-CDIM] : 0.f; w0[1] = p[0]; w0[2] = xp ? p[CDIM] : 0.f;
  }
  {
    const float* p = colbase + (size_t)y0 * 32 * CDIM;
    w1[0] = xm ? p[-CDIM] : 0.f; w1[1] = p[0]; w1[2] = xp ? p[CDIM] : 0.f;
  }

  for (int y = y0; y < y0 + 16; y++) {
    if (y + 1 < 32) {
      const float* p = colbase + (size_t)(y + 1) * 32 * CDIM;
      w2[0] = xm ? p[-CDIM] : 0.f; w2[1] = p[0]; w2[2] = xp ? p[CDIM] : 0.f;
    } else {
      w2[0] = w2[1] = w2[2] = 0.f;
    }
    float acc = w0[0] * w[0] + w0[1] * w[1] + w0[2] * w[2]
              + w1[0] * w[3] + w1[1] * w[4] + w1[2] * w[5]
              + w2[0] * w[6] + w2[1] * w[7] + w2[2] * w[8];
    float r = acc * bnsc + bnsh;
    size_t tok = (size_t)(b * 1024 + y * 32 + x);
    X2[tok * CDIM + c] = r;

    float s1 = r, s2 = r * r;
#pragma unroll
    for (int o = 32; o > 0; o >>= 1) { s1 += __shfl_xor(s1, o); s2 += __shfl_xor(s2, o); }
    int pb = y & 1;
    if (ln == 0) { part[pb][wv][0] = s1; part[pb][wv][1] = s2; }
    __syncthreads();
    float ts1 = 0.f, ts2 = 0.f;
#pragma unroll
    for (int i = 0; i < 6; i++) { ts1 += part[pb][i][0]; ts2 += part[pb][i][1]; }
    float mean = ts1 * (1.f / 384.f);
    float var = ts2 * (1.f / 384.f) - mean * mean;
    float rstd = rsqrtf(var + 1e-5f);
    XN[tok * CDIM + c] = __float2bfloat16((r - mean) * rstd * lgc + lbc);

    w0[0] = w1[0]; w0[1] = w1[1]; w0[2] = w1[2];
    w1[0] = w2[0]; w1[1] = w2[1]; w1[2] = w2[2];
  }
}

extern "C" void kernel_launch(void* const* d_in, const int* in_sizes, int n_in,
                              void* d_out, int out_size, void* d_ws, size_t ws_size,
                              hipStream_t stream) {
  const float* x      = (const float*)d_in[0];
  const float* ln1_g  = (const float*)d_in[1];
  const float* ln1_b  = (const float*)d_in[2];
  const float* qkv_w  = (const float*)d_in[3];
  const float* qkv_b  = (const float*)d_in[4];
  const float* proj_w = (const float*)d_in[5];
  const float* proj_b = (const float*)d_in[6];
  const float* att_b  = (const float*)d_in[7];
  const float* conv_w = (const float*)d_in[8];
  const float* bn_g   = (const float*)d_in[9];
  const float* bn_b   = (const float*)d_in[10];
  const float* bn_m   = (const float*)d_in[11];
  const float* bn_v   = (const float*)d_in[12];
  const float* ln2_g  = (const float*)d_in[13];
  const float* ln2_b  = (const float*)d_in[14];
  const float* fc1_w  = (const float*)d_in[15];
  const float* fc1_b  = (const float*)d_in[16];
  const float* fc2_w  = (const float*)d_in[17];
  const float* fc2_b  = (const float*)d_in[18];
  const int* bias_idxs = (const int*)d_in[19];
  int n_off = in_sizes[7] / NHEAD;
  float* out = (float*)d_out;

  char* ws = (char*)d_ws;
  size_t off = 0;
  __hip_bfloat16* qkv_pad = (__hip_bfloat16*)(ws + off); off += QKVC * 2;
  off = (off + 255) & ~(size_t)255;
  float* Bexp = (float*)(ws + off); off += (size_t)NHEAD * 4096 * 4;
  __hip_bfloat16* wqkvT = (__hip_bfloat16*)(ws + off); off += (size_t)QKVC * CDIM * 2;
  __hip_bfloat16* wprojT = (__hip_bfloat16*)(ws + off); off += (size_t)CDIM * CDIM * 2;
  __hip_bfloat16* wfc1T = (__hip_bfloat16*)(ws + off); off += (size_t)MLPH * CDIM * 2;
  __hip_bfloat16* wfc2T = (__hip_bfloat16*)(ws + off); off += (size_t)CDIM * MLPH * 2;
  size_t HDR = (off + 255) & ~(size_t)255;

  const size_t PER_TOK = 9984;
  int Bc = 64;
  while (Bc > 1 && HDR + (size_t)Bc * 1024 * PER_TOK > ws_size) Bc >>= 1;
  size_t Tc = (size_t)Bc * 1024;

  off = HDR;
  __hip_bfloat16* xn = (__hip_bfloat16*)(ws + off); off += Tc * CDIM * 2;
  __hip_bfloat16* qkv = (__hip_bfloat16*)(ws + off); off += Tc * QKVC * 2;
  __hip_bfloat16* awb = (__hip_bfloat16*)(ws + off); off += Tc * CDIM * 2;
  float* x1 = (float*)(ws + off); off += Tc * CDIM * 4;
  float* x2 = (float*)(ws + off); off += Tc * CDIM * 4;
  __hip_bfloat16* hb = (__hip_bfloat16*)(ws + off); off += Tc * MLPH * 2;

  pad_qkv_kernel<<<dim3(5), dim3(256), 0, stream>>>(ln1_b, qkv_w, qkv_b, qkv_pad);
  expand_bias<<<dim3(NHEAD), dim3(256), 0, stream>>>(att_b, bias_idxs, Bexp, n_off);
  wt_convert<<<dim3(QKVC / 32, CDIM / 32), dim3(32, 8), 0, stream>>>(qkv_w, wqkvT, CDIM, QKVC);
  wt_convert<<<dim3(CDIM / 32, CDIM / 32), dim3(32, 8), 0, stream>>>(proj_w, wprojT, CDIM, CDIM);
  wt_convert<<<dim3(MLPH / 32, CDIM / 32), dim3(32, 8), 0, stream>>>(fc1_w, wfc1T, CDIM, MLPH);
  wt_convert<<<dim3(CDIM / 32, MLPH / 32), dim3(32, 8), 0, stream>>>(fc2_w, wfc2T, MLPH, CDIM);

  for (int b0 = 0; b0 < 64; b0 += Bc) {
    const float* xa = x + (size_t)b0 * 1024 * CDIM;
    float* outa = out + (size_t)b0 * 1024 * CDIM;
    int M = (int)Tc;
    int mt = M / 128;

    ln_kernel<<<dim3(M / 4), dim3(256), 0, stream>>>(xa, ln1_g, ln1_b, xn, M);
    gemm_mfma<0, 0, 1><<<dim3((QKVC / 128) * mt), dim3(256), 0, stream>>>(
        xn, wqkvT, qkv_b, nullptr, qkv, M, QKVC, CDIM, QKVC / 128);
    attn_mfma<<<dim3(Bc * 25 * NHEAD), dim3(64), 0, stream>>>(qkv, qkv_pad, Bexp, awb);
    gemm_mfma<0, 1, 0><<<dim3((CDIM / 128) * mt), dim3(256), 0, stream>>>(
        awb, wprojT, proj_b, xa, x1, M, CDIM, CDIM, CDIM / 128);
    conv_bn_ln_kernel<<<dim3(Bc * 64), dim3(384), 0, stream>>>(
        x1, conv_w, bn_g, bn_b, bn_m, bn_v, ln2_g, ln2_b, x2, xn);
    gemm_mfma<1, 0, 1><<<dim3((MLPH / 128) * mt), dim3(256), 0, stream>>>(
        xn, wfc1T, fc1_b, nullptr, hb, M, MLPH, CDIM, MLPH / 128);
    gemm_mfma<0, 1, 0><<<dim3((CDIM / 128) * mt), dim3(256), 0, stream>>>(
        hb, wfc2T, fc2_b, x2, outa, M, CDIM, MLPH, CDIM / 128);
  }
}

// Round 6
// 1062.136 us; speedup vs baseline: 1.5071x; 1.5071x over previous
//
#include <hip/hip_runtime.h>
#include <hip/hip_bf16.h>
#include <math.h>

#define NHEAD 12
#define CDIM 384
#define QKVC 1152
#define MLPH 1536
#define SCALE 0.17677669529663687f  // 32^-0.5

typedef __attribute__((ext_vector_type(8))) short short8;
typedef __attribute__((ext_vector_type(4))) float f32x4;

static __device__ __forceinline__ unsigned short f2bf(float f) {
  union { __hip_bfloat16 b; unsigned short u; } c;
  c.b = __float2bfloat16(f);
  return c.u;
}

// ---------------- LN (wave per token, C=384) -> bf16 out ----------------
__global__ void ln_kernel(const float* __restrict__ X, const float* __restrict__ g,
                          const float* __restrict__ b, __hip_bfloat16* __restrict__ Y, int T) {
  int wid = (blockIdx.x * blockDim.x + threadIdx.x) >> 6;
  int lane = threadIdx.x & 63;
  if (wid >= T) return;
  const float* x = X + (size_t)wid * CDIM;
  float vals[6];
  float s = 0.f;
#pragma unroll
  for (int i = 0; i < 6; i++) { vals[i] = x[lane + i * 64]; s += vals[i]; }
#pragma unroll
  for (int o = 32; o > 0; o >>= 1) s += __shfl_xor(s, o);
  float m = s * (1.f / 384.f);
  float vs = 0.f;
#pragma unroll
  for (int i = 0; i < 6; i++) { float d = vals[i] - m; vs += d * d; }
#pragma unroll
  for (int o = 32; o > 0; o >>= 1) vs += __shfl_xor(vs, o);
  float rs = rsqrtf(vs * (1.f / 384.f) + 1e-5f);
  __hip_bfloat16* y = Y + (size_t)wid * CDIM;
#pragma unroll
  for (int i = 0; i < 6; i++) {
    int c = lane + i * 64;
    y[c] = __float2bfloat16((vals[i] - m) * rs * g[c] + b[c]);
  }
}

// ------------- qkv of a padded (zero) token: ln1_b @ qkv_w + qkv_b -> bf16 -------------
__global__ void pad_qkv_kernel(const float* __restrict__ lb, const float* __restrict__ Wq,
                               const float* __restrict__ bq, __hip_bfloat16* __restrict__ outp) {
  int j = blockIdx.x * blockDim.x + threadIdx.x;
  if (j >= QKVC) return;
  float s = bq[j];
  for (int c = 0; c < CDIM; c++) s += lb[c] * Wq[(size_t)c * QKVC + j];
  outp[j] = __float2bfloat16(s);
}

// ------------- expand relative-position bias to padded [12][64][64] f32 -------------
__global__ void expand_bias(const float* __restrict__ biases, const int* __restrict__ bidx,
                            float* __restrict__ Bexp, int n_off) {
  int h = blockIdx.x;
  for (int e = threadIdx.x; e < 4096; e += 256) {
    int n = e >> 6, m = e & 63;
    float v;
    if (m >= 49) v = -1e30f;
    else if (n >= 49) v = 0.f;
    else v = biases[h * n_off + bidx[n * 49 + m]];
    Bexp[h * 4096 + e] = v;
  }
}

// ---------------- weight transpose + f32->bf16 convert: W[K][N] -> Wt[N][K] ----------------
__global__ void wt_convert(const float* __restrict__ W, __hip_bfloat16* __restrict__ Wt,
                           int K, int N) {
  __shared__ float t[32][33];
  int n0 = blockIdx.x * 32, k0 = blockIdx.y * 32;
  int tx = threadIdx.x, ty = threadIdx.y;  // 32 x 8
#pragma unroll
  for (int i = 0; i < 4; i++) t[ty + i * 8][tx] = W[(size_t)(k0 + ty + i * 8) * N + n0 + tx];
  __syncthreads();
#pragma unroll
  for (int i = 0; i < 4; i++)
    Wt[(size_t)(n0 + ty + i * 8) * K + k0 + tx] = __float2bfloat16(t[tx][ty + i * 8]);
}

// ---------------- bf16 MFMA GEMM (R4 form): C = A @ Bt^T + bias (+res) ----------------
// Tile 128x64, BK=64, 256 threads = 4 waves (2x2), each wave 64x32 via 4x2 frags.
template <int GELU, int HAS_RES, int OUT_BF16>
__global__ __launch_bounds__(256) void gemm_mfma(
    const __hip_bfloat16* __restrict__ A, const __hip_bfloat16* __restrict__ Bt,
    const float* __restrict__ bias, const float* __restrict__ res,
    void* __restrict__ Cout, int M, int N, int K) {
  __shared__ unsigned short Al[128][72];
  __shared__ unsigned short Bl[64][72];
  int tid = threadIdx.x;
  int m0 = blockIdx.y * 128, n0 = blockIdx.x * 64;
  int wave = tid >> 6, lane = tid & 63;
  int wm = (wave >> 1) * 64, wn = (wave & 1) * 32;
  int l15 = lane & 15, l4 = lane >> 4;

  int am = tid >> 1, ak = (tid & 1) * 32;
  int bn = tid >> 2, bk = (tid & 3) * 16;
  const __hip_bfloat16* Ag = A + (size_t)(m0 + am) * K + ak;
  const __hip_bfloat16* Bg = Bt + (size_t)(n0 + bn) * K + bk;

  f32x4 acc[4][2] = {};

  for (int kt = 0; kt < K; kt += 64) {
    uint4 av0 = *(const uint4*)(Ag + kt);
    uint4 av1 = *(const uint4*)(Ag + kt + 8);
    uint4 av2 = *(const uint4*)(Ag + kt + 16);
    uint4 av3 = *(const uint4*)(Ag + kt + 24);
    uint4 bv0 = *(const uint4*)(Bg + kt);
    uint4 bv1 = *(const uint4*)(Bg + kt + 8);
    __syncthreads();
    *(uint4*)&Al[am][ak]      = av0;
    *(uint4*)&Al[am][ak + 8]  = av1;
    *(uint4*)&Al[am][ak + 16] = av2;
    *(uint4*)&Al[am][ak + 24] = av3;
    *(uint4*)&Bl[bn][bk]      = bv0;
    *(uint4*)&Bl[bn][bk + 8]  = bv1;
    __syncthreads();
#pragma unroll
    for (int kk = 0; kk < 64; kk += 32) {
      short8 af[4], bfr[2];
#pragma unroll
      for (int i = 0; i < 4; i++)
        af[i] = *(const short8*)&Al[wm + i * 16 + l15][kk + l4 * 8];
#pragma unroll
      for (int j = 0; j < 2; j++)
        bfr[j] = *(const short8*)&Bl[wn + j * 16 + l15][kk + l4 * 8];
#pragma unroll
      for (int i = 0; i < 4; i++)
#pragma unroll
        for (int j = 0; j < 2; j++)
          acc[i][j] = __builtin_amdgcn_mfma_f32_16x16x32_bf16(af[i], bfr[j], acc[i][j], 0, 0, 0);
    }
  }

#pragma unroll
  for (int i = 0; i < 4; i++) {
#pragma unroll
    for (int j = 0; j < 2; j++) {
      int n = n0 + wn + j * 16 + l15;
      float bv = bias[n];
#pragma unroll
      for (int r = 0; r < 4; r++) {
        int m = m0 + wm + i * 16 + l4 * 4 + r;
        float c = acc[i][j][r] + bv;
        if (GELU) c = 0.5f * c * (1.f + erff(c * 0.70710678118654752f));
        if (HAS_RES) c += res[(size_t)m * N + n];
        if (OUT_BF16)
          ((__hip_bfloat16*)Cout)[(size_t)m * N + n] = __float2bfloat16(c);
        else
          ((float*)Cout)[(size_t)m * N + n] = c;
      }
    }
  }
}

// ---------------- fused MLP: OUT = gelu(XN @ W1 + b1) @ W2 + b2 + X2 ----------------
// Block = 64 rows, 512 threads = 8 waves (2m x 4n). 12 slabs of 128 h-cols; the
// 64x128 h slab lives only in LDS (bf16), C (64x384 f32) stays in registers.
// W1T [1536][384], W2T [384][1536] bf16 (pre-transposed); both fit in each XCD L2.
__global__ __launch_bounds__(512) void mlp_fused(
    const __hip_bfloat16* __restrict__ XN, const __hip_bfloat16* __restrict__ W1T,
    const float* __restrict__ B1, const __hip_bfloat16* __restrict__ W2T,
    const float* __restrict__ B2, const float* __restrict__ X2,
    float* __restrict__ OUT) {
  __shared__ unsigned short XNl[64][392];  // pitch 392: +4 words/row -> optimal b128 banking
  __shared__ unsigned short Hl[64][136];
  int tid = threadIdx.x;
  int m0 = blockIdx.x * 64;
  int wave = tid >> 6, lane = tid & 63;
  int wm = (wave >> 2) * 32;  // wave m-offset (2 m-groups)
  int wn = wave & 3;          // wave n-group (4)
  int l15 = lane & 15, l4 = lane >> 4;

  {  // stage A panel 64x384 bf16 (each thread 48 shorts)
    int r = tid >> 3, seg = (tid & 7) * 48;
    const unsigned short* src = (const unsigned short*)XN + (size_t)(m0 + r) * 384 + seg;
#pragma unroll
    for (int i = 0; i < 6; i++)
      *(uint4*)&XNl[r][seg + i * 8] = *(const uint4*)(src + i * 8);
  }

  f32x4 acc[2][6] = {};
  __syncthreads();

  for (int ks = 0; ks < 12; ks++) {
    // ---- phase 1: hacc = XN_panel @ W1T[slab]^T (A from LDS, B from L2) ----
    f32x4 hacc[2][2] = {};
    const unsigned short* w1b =
        (const unsigned short*)W1T + ((size_t)ks * 128 + wn * 32) * 384 + l4 * 8;
#pragma unroll
    for (int kk = 0; kk < 384; kk += 32) {
      short8 bf0 = *(const short8*)(w1b + (size_t)l15 * 384 + kk);
      short8 bf1 = *(const short8*)(w1b + (size_t)(16 + l15) * 384 + kk);
      short8 af0 = *(const short8*)&XNl[wm + l15][kk + l4 * 8];
      short8 af1 = *(const short8*)&XNl[wm + 16 + l15][kk + l4 * 8];
      hacc[0][0] = __builtin_amdgcn_mfma_f32_16x16x32_bf16(af0, bf0, hacc[0][0], 0, 0, 0);
      hacc[0][1] = __builtin_amdgcn_mfma_f32_16x16x32_bf16(af0, bf1, hacc[0][1], 0, 0, 0);
      hacc[1][0] = __builtin_amdgcn_mfma_f32_16x16x32_bf16(af1, bf0, hacc[1][0], 0, 0, 0);
      hacc[1][1] = __builtin_amdgcn_mfma_f32_16x16x32_bf16(af1, bf1, hacc[1][1], 0, 0, 0);
    }
    float b10 = B1[ks * 128 + wn * 32 + l15];
    float b11 = B1[ks * 128 + wn * 32 + 16 + l15];
    __syncthreads();  // prior slab's phase-2 reads of Hl done
#pragma unroll
    for (int i = 0; i < 2; i++)
#pragma unroll
      for (int j = 0; j < 2; j++) {
        float bv = j ? b11 : b10;
#pragma unroll
        for (int r = 0; r < 4; r++) {
          float c = hacc[i][j][r] + bv;
          c = 0.5f * c * (1.f + erff(c * 0.70710678118654752f));
          Hl[wm + i * 16 + l4 * 4 + r][wn * 32 + j * 16 + l15] = f2bf(c);
        }
      }
    __syncthreads();
    // ---- phase 2: acc += Hl @ W2T[:, slab]^T ----
    const unsigned short* w2b = (const unsigned short*)W2T + (size_t)ks * 128 + l4 * 8;
#pragma unroll
    for (int kk = 0; kk < 128; kk += 32) {
      short8 af20 = *(const short8*)&Hl[wm + l15][kk + l4 * 8];
      short8 af21 = *(const short8*)&Hl[wm + 16 + l15][kk + l4 * 8];
#pragma unroll
      for (int j = 0; j < 6; j++) {
        short8 bf2 = *(const short8*)(w2b + (size_t)(wn * 96 + j * 16 + l15) * 1536 + kk);
        acc[0][j] = __builtin_amdgcn_mfma_f32_16x16x32_bf16(af20, bf2, acc[0][j], 0, 0, 0);
        acc[1][j] = __builtin_amdgcn_mfma_f32_16x16x32_bf16(af21, bf2, acc[1][j], 0, 0, 0);
      }
    }
  }
  // ---- epilogue: + b2 + residual ----
#pragma unroll
  for (int i = 0; i < 2; i++)
#pragma unroll
    for (int j = 0; j < 6; j++) {
      int n = wn * 96 + j * 16 + l15;
      float bv = B2[n];
#pragma unroll
      for (int r = 0; r < 4; r++) {
        int m = m0 + wm + i * 16 + l4 * 4 + r;
        OUT[(size_t)m * 384 + n] = acc[i][j][r] + bv + X2[(size_t)m * 384 + n];
      }
    }
}

// ---------------- MFMA window attention: 1 wave per (window, head) ----------------
__global__ __launch_bounds__(64) void attn_mfma(
    const __hip_bfloat16* __restrict__ qkv, const __hip_bfloat16* __restrict__ qkv_pad,
    const float* __restrict__ Bexp, __hip_bfloat16* __restrict__ aw) {
  int h = blockIdx.x % NHEAD;
  int w = blockIdx.x / NHEAD;
  int b = w / 25, wi = w % 25;
  int wh = wi / 5, wv = wi % 5;

  __shared__ unsigned short Q[64][40];
  __shared__ unsigned short K[64][40];
  __shared__ unsigned short Vt[32][72];
  __shared__ unsigned short P[64][72];

  int lane = threadIdx.x;
  int l15 = lane & 15, l4 = lane >> 4;

  {
    int t = lane;
    uint4 z = {0, 0, 0, 0};
    uint4 qv[4], kv[4];
    union { uint4 u[4]; unsigned short s[32]; } vu;
    bool use = t < 49;
    const unsigned short* src = (const unsigned short*)qkv_pad + h * 96;
    if (use) {
      int hh = wh * 7 + t / 7, ww = wv * 7 + t % 7;
      if (hh < 32 && ww < 32)
        src = (const unsigned short*)qkv + (size_t)(b * 1024 + hh * 32 + ww) * QKVC + h * 96;
    }
#pragma unroll
    for (int c = 0; c < 4; c++) {
      qv[c]   = use ? *(const uint4*)(src + c * 8)      : z;
      kv[c]   = use ? *(const uint4*)(src + 32 + c * 8) : z;
      vu.u[c] = use ? *(const uint4*)(src + 64 + c * 8) : z;
    }
#pragma unroll
    for (int c = 0; c < 4; c++) {
      *(uint4*)&Q[t][c * 8] = qv[c];
      *(uint4*)&K[t][c * 8] = kv[c];
    }
#pragma unroll
    for (int d = 0; d < 32; d++) Vt[d][t] = vu.s[d];
  }
  __syncthreads();

  f32x4 acc[4][4] = {};
  {
    short8 aq[4], bk[4];
#pragma unroll
    for (int i = 0; i < 4; i++) aq[i] = *(const short8*)&Q[i * 16 + l15][l4 * 8];
#pragma unroll
    for (int j = 0; j < 4; j++) bk[j] = *(const short8*)&K[j * 16 + l15][l4 * 8];
#pragma unroll
    for (int i = 0; i < 4; i++)
#pragma unroll
      for (int j = 0; j < 4; j++)
        acc[i][j] = __builtin_amdgcn_mfma_f32_16x16x32_bf16(aq[i], bk[j], acc[i][j], 0, 0, 0);
  }

  const float* Bh = Bexp + h * 4096;
  float rinv_[4][4];
#pragma unroll
  for (int i = 0; i < 4; i++) {
    float s[4][4];
#pragma unroll
    for (int j = 0; j < 4; j++)
#pragma unroll
      for (int r = 0; r < 4; r++) {
        int n = i * 16 + l4 * 4 + r, m = j * 16 + l15;
        s[j][r] = acc[i][j][r] * SCALE + Bh[n * 64 + m];
      }
#pragma unroll
    for (int r = 0; r < 4; r++) {
      float mx = fmaxf(fmaxf(s[0][r], s[1][r]), fmaxf(s[2][r], s[3][r]));
#pragma unroll
      for (int o = 1; o < 16; o <<= 1) mx = fmaxf(mx, __shfl_xor(mx, o));
      float p[4], sm = 0.f;
#pragma unroll
      for (int j = 0; j < 4; j++) { p[j] = __expf(s[j][r] - mx); sm += p[j]; }
#pragma unroll
      for (int o = 1; o < 16; o <<= 1) sm += __shfl_xor(sm, o);
      rinv_[i][r] = 1.f / sm;
      int n = i * 16 + l4 * 4 + r;
#pragma unroll
      for (int j = 0; j < 4; j++) P[n][j * 16 + l15] = f2bf(p[j]);
    }
  }
  __syncthreads();

  f32x4 o[4][2] = {};
#pragma unroll
  for (int ks = 0; ks < 2; ks++) {
    short8 pa[4], vb[2];
#pragma unroll
    for (int i = 0; i < 4; i++) pa[i] = *(const short8*)&P[i * 16 + l15][ks * 32 + l4 * 8];
#pragma unroll
    for (int j = 0; j < 2; j++) vb[j] = *(const short8*)&Vt[j * 16 + l15][ks * 32 + l4 * 8];
#pragma unroll
    for (int i = 0; i < 4; i++)
#pragma unroll
      for (int j = 0; j < 2; j++)
        o[i][j] = __builtin_amdgcn_mfma_f32_16x16x32_bf16(pa[i], vb[j], o[i][j], 0, 0, 0);
  }

#pragma unroll
  for (int i = 0; i < 4; i++)
#pragma unroll
    for (int r = 0; r < 4; r++) {
      int n = i * 16 + l4 * 4 + r;
      if (n < 49) {
        int hh = wh * 7 + n / 7, ww = wv * 7 + n % 7;
        if (hh < 32 && ww < 32) {
          __hip_bfloat16* dst = aw + (size_t)(b * 1024 + hh * 32 + ww) * CDIM + h * 32;
          float ri = rinv_[i][r];
#pragma unroll
          for (int j = 0; j < 2; j++)
            dst[j * 16 + l15] = __float2bfloat16(o[i][j][r] * ri);
        }
      }
    }
}

// ------- fused depthwise 3x3 conv + BN + LN2: block = (b, x, y-half), thread = channel -------
__global__ __launch_bounds__(384) void conv_bn_ln_kernel(
    const float* __restrict__ X, const float* __restrict__ W9,
    const float* __restrict__ g, const float* __restrict__ bb,
    const float* __restrict__ mm, const float* __restrict__ vv,
    const float* __restrict__ lg, const float* __restrict__ lb,
    float* __restrict__ X2, __hip_bfloat16* __restrict__ XN) {
  int nwg = gridDim.x;
  int id = blockIdx.x;
  int nid = (id & 7) * (nwg >> 3) + (id >> 3);
  int yh = nid & 1;
  int x = (nid >> 1) & 31;
  int b = nid >> 6;
  int c = threadIdx.x;

  float w[9];
#pragma unroll
  for (int i = 0; i < 9; i++) w[i] = W9[c * 9 + i];
  float bnsc = rsqrtf(vv[c] + 1e-5f) * g[c];
  float bnsh = bb[c] - mm[c] * bnsc;
  float lgc = lg[c], lbc = lb[c];

  bool xm = x > 0, xp = x < 31;
  const float* colbase = X + ((size_t)(b * 1024 + x)) * CDIM + c;

  __shared__ float part[2][6][2];
  int wv = threadIdx.x >> 6, ln = threadIdx.x & 63;

  float w0[3], w1[3], w2[3];
  int y0 = yh * 16;
  if (y0 == 0) {
    w0[0] = w0[1] = w0[2] = 0.f;
  } else {
    const float* p = colbase + (size_t)(y0 - 1) * 32 * CDIM;
    w0[0] = xm ? p[-CDIM] : 0.f; w0[1] = p[0]; w0[2] = xp ? p[CDIM] : 0.f;
  }
  {
    const float* p = colbase + (size_t)y0 * 32 * CDIM;
    w1[0] = xm ? p[-CDIM] : 0.f; w1[1] = p[0]; w1[2] = xp ? p[CDIM] : 0.f;
  }

  for (int y = y0; y < y0 + 16; y++) {
    if (y + 1 < 32) {
      const float* p = colbase + (size_t)(y + 1) * 32 * CDIM;
      w2[0] = xm ? p[-CDIM] : 0.f; w2[1] = p[0]; w2[2] = xp ? p[CDIM] : 0.f;
    } else {
      w2[0] = w2[1] = w2[2] = 0.f;
    }
    float acc = w0[0] * w[0] + w0[1] * w[1] + w0[2] * w[2]
              + w1[0] * w[3] + w1[1] * w[4] + w1[2] * w[5]
              + w2[0] * w[6] + w2[1] * w[7] + w2[2] * w[8];
    float r = acc * bnsc + bnsh;
    size_t tok = (size_t)(b * 1024 + y * 32 + x);
    X2[tok * CDIM + c] = r;

    float s1 = r, s2 = r * r;
#pragma unroll
    for (int o = 32; o > 0; o >>= 1) { s1 += __shfl_xor(s1, o); s2 += __shfl_xor(s2, o); }
    int pb = y & 1;
    if (ln == 0) { part[pb][wv][0] = s1; part[pb][wv][1] = s2; }
    __syncthreads();
    float ts1 = 0.f, ts2 = 0.f;
#pragma unroll
    for (int i = 0; i < 6; i++) { ts1 += part[pb][i][0]; ts2 += part[pb][i][1]; }
    float mean = ts1 * (1.f / 384.f);
    float var = ts2 * (1.f / 384.f) - mean * mean;
    float rstd = rsqrtf(var + 1e-5f);
    XN[tok * CDIM + c] = __float2bfloat16((r - mean) * rstd * lgc + lbc);

    w0[0] = w1[0]; w0[1] = w1[1]; w0[2] = w1[2];
    w1[0] = w2[0]; w1[1] = w2[1]; w1[2] = w2[2];
  }
}

extern "C" void kernel_launch(void* const* d_in, const int* in_sizes, int n_in,
                              void* d_out, int out_size, void* d_ws, size_t ws_size,
                              hipStream_t stream) {
  const float* x      = (const float*)d_in[0];
  const float* ln1_g  = (const float*)d_in[1];
  const float* ln1_b  = (const float*)d_in[2];
  const float* qkv_w  = (const float*)d_in[3];
  const float* qkv_b  = (const float*)d_in[4];
  const float* proj_w = (const float*)d_in[5];
  const float* proj_b = (const float*)d_in[6];
  const float* att_b  = (const float*)d_in[7];
  const float* conv_w = (const float*)d_in[8];
  const float* bn_g   = (const float*)d_in[9];
  const float* bn_b   = (const float*)d_in[10];
  const float* bn_m   = (const float*)d_in[11];
  const float* bn_v   = (const float*)d_in[12];
  const float* ln2_g  = (const float*)d_in[13];
  const float* ln2_b  = (const float*)d_in[14];
  const float* fc1_w  = (const float*)d_in[15];
  const float* fc1_b  = (const float*)d_in[16];
  const float* fc2_w  = (const float*)d_in[17];
  const float* fc2_b  = (const float*)d_in[18];
  const int* bias_idxs = (const int*)d_in[19];
  int n_off = in_sizes[7] / NHEAD;
  float* out = (float*)d_out;

  char* ws = (char*)d_ws;
  size_t off = 0;
  __hip_bfloat16* qkv_pad = (__hip_bfloat16*)(ws + off); off += QKVC * 2;
  off = (off + 255) & ~(size_t)255;
  float* Bexp = (float*)(ws + off); off += (size_t)NHEAD * 4096 * 4;
  __hip_bfloat16* wqkvT = (__hip_bfloat16*)(ws + off); off += (size_t)QKVC * CDIM * 2;
  __hip_bfloat16* wprojT = (__hip_bfloat16*)(ws + off); off += (size_t)CDIM * CDIM * 2;
  __hip_bfloat16* wfc1T = (__hip_bfloat16*)(ws + off); off += (size_t)MLPH * CDIM * 2;
  __hip_bfloat16* wfc2T = (__hip_bfloat16*)(ws + off); off += (size_t)CDIM * MLPH * 2;
  size_t HDR = (off + 255) & ~(size_t)255;

  // per-token chunk scratch: xn bf16(768) + qkv bf16(2304) + awb bf16(768)
  //                        + x1 f32(1536) + x2 f32(1536) = 6912 B
  const size_t PER_TOK = 6912;
  int Bc = 64;
  while (Bc > 1 && HDR + (size_t)Bc * 1024 * PER_TOK > ws_size) Bc >>= 1;
  size_t Tc = (size_t)Bc * 1024;

  off = HDR;
  __hip_bfloat16* xn = (__hip_bfloat16*)(ws + off); off += Tc * CDIM * 2;
  __hip_bfloat16* qkv = (__hip_bfloat16*)(ws + off); off += Tc * QKVC * 2;
  __hip_bfloat16* awb = (__hip_bfloat16*)(ws + off); off += Tc * CDIM * 2;
  float* x1 = (float*)(ws + off); off += Tc * CDIM * 4;
  float* x2 = (float*)(ws + off); off += Tc * CDIM * 4;

  pad_qkv_kernel<<<dim3(5), dim3(256), 0, stream>>>(ln1_b, qkv_w, qkv_b, qkv_pad);
  expand_bias<<<dim3(NHEAD), dim3(256), 0, stream>>>(att_b, bias_idxs, Bexp, n_off);
  wt_convert<<<dim3(QKVC / 32, CDIM / 32), dim3(32, 8), 0, stream>>>(qkv_w, wqkvT, CDIM, QKVC);
  wt_convert<<<dim3(CDIM / 32, CDIM / 32), dim3(32, 8), 0, stream>>>(proj_w, wprojT, CDIM, CDIM);
  wt_convert<<<dim3(MLPH / 32, CDIM / 32), dim3(32, 8), 0, stream>>>(fc1_w, wfc1T, CDIM, MLPH);
  wt_convert<<<dim3(CDIM / 32, MLPH / 32), dim3(32, 8), 0, stream>>>(fc2_w, wfc2T, MLPH, CDIM);

  for (int b0 = 0; b0 < 64; b0 += Bc) {
    const float* xa = x + (size_t)b0 * 1024 * CDIM;
    float* outa = out + (size_t)b0 * 1024 * CDIM;
    int M = (int)Tc;

    ln_kernel<<<dim3(M / 4), dim3(256), 0, stream>>>(xa, ln1_g, ln1_b, xn, M);
    gemm_mfma<0, 0, 1><<<dim3(QKVC / 64, M / 128), dim3(256), 0, stream>>>(
        xn, wqkvT, qkv_b, nullptr, qkv, M, QKVC, CDIM);
    attn_mfma<<<dim3(Bc * 25 * NHEAD), dim3(64), 0, stream>>>(qkv, qkv_pad, Bexp, awb);
    gemm_mfma<0, 1, 0><<<dim3(CDIM / 64, M / 128), dim3(256), 0, stream>>>(
        awb, wprojT, proj_b, xa, x1, M, CDIM, CDIM);
    conv_bn_ln_kernel<<<dim3(Bc * 64), dim3(384), 0, stream>>>(
        x1, conv_w, bn_g, bn_b, bn_m, bn_v, ln2_g, ln2_b, x2, xn);
    mlp_fused<<<dim3(M / 64), dim3(512), 0, stream>>>(
        xn, wfc1T, fc1_b, wfc2T, fc2_b, x2, outa);
  }
}

// Round 7
// 826.027 us; speedup vs baseline: 1.9378x; 1.2858x over previous
//
#include <hip/hip_runtime.h>
#include <hip/hip_bf16.h>
#include <math.h>

#define NHEAD 12
#define CDIM 384
#define QKVC 1152
#define MLPH 1536
#define SCALE 0.17677669529663687f  // 32^-0.5

typedef __attribute__((ext_vector_type(8))) short short8;
typedef __attribute__((ext_vector_type(4))) float f32x4;

static __device__ __forceinline__ unsigned short f2bf(float f) {
  union { __hip_bfloat16 b; unsigned short u; } c;
  c.b = __float2bfloat16(f);
  return c.u;
}

// ---------------- LN (wave per token, C=384) -> bf16 out ----------------
__global__ void ln_kernel(const float* __restrict__ X, const float* __restrict__ g,
                          const float* __restrict__ b, __hip_bfloat16* __restrict__ Y, int T) {
  int wid = (blockIdx.x * blockDim.x + threadIdx.x) >> 6;
  int lane = threadIdx.x & 63;
  if (wid >= T) return;
  const float* x = X + (size_t)wid * CDIM;
  float vals[6];
  float s = 0.f;
#pragma unroll
  for (int i = 0; i < 6; i++) { vals[i] = x[lane + i * 64]; s += vals[i]; }
#pragma unroll
  for (int o = 32; o > 0; o >>= 1) s += __shfl_xor(s, o);
  float m = s * (1.f / 384.f);
  float vs = 0.f;
#pragma unroll
  for (int i = 0; i < 6; i++) { float d = vals[i] - m; vs += d * d; }
#pragma unroll
  for (int o = 32; o > 0; o >>= 1) vs += __shfl_xor(vs, o);
  float rs = rsqrtf(vs * (1.f / 384.f) + 1e-5f);
  __hip_bfloat16* y = Y + (size_t)wid * CDIM;
#pragma unroll
  for (int i = 0; i < 6; i++) {
    int c = lane + i * 64;
    y[c] = __float2bfloat16((vals[i] - m) * rs * g[c] + b[c]);
  }
}

// ------------- qkv of a padded (zero) token: ln1_b @ qkv_w + qkv_b -> bf16 -------------
__global__ void pad_qkv_kernel(const float* __restrict__ lb, const float* __restrict__ Wq,
                               const float* __restrict__ bq, __hip_bfloat16* __restrict__ outp) {
  int j = blockIdx.x * blockDim.x + threadIdx.x;
  if (j >= QKVC) return;
  float s = bq[j];
  for (int c = 0; c < CDIM; c++) s += lb[c] * Wq[(size_t)c * QKVC + j];
  outp[j] = __float2bfloat16(s);
}

// ------------- expand relative-position bias to padded [12][64][64] f32 -------------
__global__ void expand_bias(const float* __restrict__ biases, const int* __restrict__ bidx,
                            float* __restrict__ Bexp, int n_off) {
  int h = blockIdx.x;
  for (int e = threadIdx.x; e < 4096; e += 256) {
    int n = e >> 6, m = e & 63;
    float v;
    if (m >= 49) v = -1e30f;
    else if (n >= 49) v = 0.f;
    else v = biases[h * n_off + bidx[n * 49 + m]];
    Bexp[h * 4096 + e] = v;
  }
}

// ---------------- weight transpose + f32->bf16 convert: W[K][N] -> Wt[N][K] ----------------
__global__ void wt_convert(const float* __restrict__ W, __hip_bfloat16* __restrict__ Wt,
                           int K, int N) {
  __shared__ float t[32][33];
  int n0 = blockIdx.x * 32, k0 = blockIdx.y * 32;
  int tx = threadIdx.x, ty = threadIdx.y;  // 32 x 8
#pragma unroll
  for (int i = 0; i < 4; i++) t[ty + i * 8][tx] = W[(size_t)(k0 + ty + i * 8) * N + n0 + tx];
  __syncthreads();
#pragma unroll
  for (int i = 0; i < 4; i++)
    Wt[(size_t)(n0 + ty + i * 8) * K + k0 + tx] = __float2bfloat16(t[tx][ty + i * 8]);
}

// -------- pack fc1_w [384][1536] into phase-1 MFMA fragment order --------
// frag f = ks*96 + kk*8 + wn*2 + half (1152 frags); lane holds B[n][k]:
// n = ks*128+wn*32+half*16+(lane&15), k = kk*32+(lane>>4)*8+j
__global__ void wfrag1(const float* __restrict__ W, unsigned short* __restrict__ WF) {
  int f = blockIdx.x;
  int lane = threadIdx.x;
  int half = f & 1, wn = (f >> 1) & 3, kk = (f >> 3) % 12, ks = f / 96;
  int n = ks * 128 + wn * 32 + half * 16 + (lane & 15);
  int k = kk * 32 + (lane >> 4) * 8;
  unsigned short* dst = WF + ((size_t)f * 64 + lane) * 8;
#pragma unroll
  for (int j = 0; j < 8; j++) dst[j] = f2bf(W[(size_t)(k + j) * MLPH + n]);
}

// -------- pack fc2_w [1536][384] into phase-2 MFMA fragment order --------
// frag f = ks*96 + kk*24 + wn*6 + j (1152 frags); lane holds B[n][k]:
// n = wn*96+j*16+(lane&15), k = ks*128+kk*32+(lane>>4)*8+jj
__global__ void wfrag2(const float* __restrict__ W, unsigned short* __restrict__ WF) {
  int f = blockIdx.x;
  int lane = threadIdx.x;
  int j = f % 6, wn = (f / 6) & 3, kk = (f / 24) & 3, ks = f / 96;
  int n = wn * 96 + j * 16 + (lane & 15);
  int k = ks * 128 + kk * 32 + (lane >> 4) * 8;
  unsigned short* dst = WF + ((size_t)f * 64 + lane) * 8;
#pragma unroll
  for (int jj = 0; jj < 8; jj++) dst[jj] = f2bf(W[(size_t)(k + jj) * CDIM + n]);
}

// ---------------- bf16 MFMA GEMM (R4 form): C = A @ Bt^T + bias (+res) ----------------
template <int GELU, int HAS_RES, int OUT_BF16>
__global__ __launch_bounds__(256) void gemm_mfma(
    const __hip_bfloat16* __restrict__ A, const __hip_bfloat16* __restrict__ Bt,
    const float* __restrict__ bias, const float* __restrict__ res,
    void* __restrict__ Cout, int M, int N, int K) {
  __shared__ unsigned short Al[128][72];
  __shared__ unsigned short Bl[64][72];
  int tid = threadIdx.x;
  int m0 = blockIdx.y * 128, n0 = blockIdx.x * 64;
  int wave = tid >> 6, lane = tid & 63;
  int wm = (wave >> 1) * 64, wn = (wave & 1) * 32;
  int l15 = lane & 15, l4 = lane >> 4;

  int am = tid >> 1, ak = (tid & 1) * 32;
  int bn = tid >> 2, bk = (tid & 3) * 16;
  const __hip_bfloat16* Ag = A + (size_t)(m0 + am) * K + ak;
  const __hip_bfloat16* Bg = Bt + (size_t)(n0 + bn) * K + bk;

  f32x4 acc[4][2] = {};

  for (int kt = 0; kt < K; kt += 64) {
    uint4 av0 = *(const uint4*)(Ag + kt);
    uint4 av1 = *(const uint4*)(Ag + kt + 8);
    uint4 av2 = *(const uint4*)(Ag + kt + 16);
    uint4 av3 = *(const uint4*)(Ag + kt + 24);
    uint4 bv0 = *(const uint4*)(Bg + kt);
    uint4 bv1 = *(const uint4*)(Bg + kt + 8);
    __syncthreads();
    *(uint4*)&Al[am][ak]      = av0;
    *(uint4*)&Al[am][ak + 8]  = av1;
    *(uint4*)&Al[am][ak + 16] = av2;
    *(uint4*)&Al[am][ak + 24] = av3;
    *(uint4*)&Bl[bn][bk]      = bv0;
    *(uint4*)&Bl[bn][bk + 8]  = bv1;
    __syncthreads();
#pragma unroll
    for (int kk = 0; kk < 64; kk += 32) {
      short8 af[4], bfr[2];
#pragma unroll
      for (int i = 0; i < 4; i++)
        af[i] = *(const short8*)&Al[wm + i * 16 + l15][kk + l4 * 8];
#pragma unroll
      for (int j = 0; j < 2; j++)
        bfr[j] = *(const short8*)&Bl[wn + j * 16 + l15][kk + l4 * 8];
#pragma unroll
      for (int i = 0; i < 4; i++)
#pragma unroll
        for (int j = 0; j < 2; j++)
          acc[i][j] = __builtin_amdgcn_mfma_f32_16x16x32_bf16(af[i], bfr[j], acc[i][j], 0, 0, 0);
    }
  }

#pragma unroll
  for (int i = 0; i < 4; i++) {
#pragma unroll
    for (int j = 0; j < 2; j++) {
      int n = n0 + wn + j * 16 + l15;
      float bv = bias[n];
#pragma unroll
      for (int r = 0; r < 4; r++) {
        int m = m0 + wm + i * 16 + l4 * 4 + r;
        float c = acc[i][j][r] + bv;
        if (GELU) c = 0.5f * c * (1.f + erff(c * 0.70710678118654752f));
        if (HAS_RES) c += res[(size_t)m * N + n];
        if (OUT_BF16)
          ((__hip_bfloat16*)Cout)[(size_t)m * N + n] = __float2bfloat16(c);
        else
          ((float*)Cout)[(size_t)m * N + n] = c;
      }
    }
  }
}

// ---------------- fused MLP: OUT = gelu(XN @ W1 + b1) @ W2 + b2 + X2 ----------------
// Weights pre-packed in fragment order (W1F/W2F): every weight load is one
// coalesced 1KB wave transaction from L2. Block = 64 rows, 8 waves (2m x 4n).
__global__ __launch_bounds__(512) void mlp_fused(
    const __hip_bfloat16* __restrict__ XN, const unsigned short* __restrict__ W1F,
    const float* __restrict__ B1, const unsigned short* __restrict__ W2F,
    const float* __restrict__ B2, const float* __restrict__ X2,
    float* __restrict__ OUT) {
  __shared__ unsigned short XNl[64][392];
  __shared__ unsigned short Hl[64][136];
  int tid = threadIdx.x;
  int m0 = blockIdx.x * 64;
  int wave = tid >> 6, lane = tid & 63;
  int wm = (wave >> 2) * 32;
  int wn = wave & 3;
  int l15 = lane & 15, l4 = lane >> 4;

  {  // stage A panel 64x384 bf16, fully coalesced uint4 order
#pragma unroll
    for (int i = 0; i < 6; i++) {
      int u = tid + i * 512;
      int r = u / 48, col = (u % 48) * 8;
      *(uint4*)&XNl[r][col] =
          *(const uint4*)((const unsigned short*)XN + (size_t)(m0 + r) * 384 + col);
    }
  }

  f32x4 acc[2][6] = {};
  __syncthreads();

  for (int ks = 0; ks < 12; ks++) {
    // ---- phase 1: hacc = XN_panel @ W1 slab (B frags coalesced from L2) ----
    f32x4 hacc[2][2] = {};
    const unsigned short* w1fb = W1F + ((size_t)(ks * 96 + wn * 2)) * 512 + lane * 8;
#pragma unroll
    for (int kk = 0; kk < 12; kk++) {
      short8 bf0 = *(const short8*)(w1fb + kk * 4096);
      short8 bf1 = *(const short8*)(w1fb + kk * 4096 + 512);
      short8 af0 = *(const short8*)&XNl[wm + l15][kk * 32 + l4 * 8];
      short8 af1 = *(const short8*)&XNl[wm + 16 + l15][kk * 32 + l4 * 8];
      hacc[0][0] = __builtin_amdgcn_mfma_f32_16x16x32_bf16(af0, bf0, hacc[0][0], 0, 0, 0);
      hacc[0][1] = __builtin_amdgcn_mfma_f32_16x16x32_bf16(af0, bf1, hacc[0][1], 0, 0, 0);
      hacc[1][0] = __builtin_amdgcn_mfma_f32_16x16x32_bf16(af1, bf0, hacc[1][0], 0, 0, 0);
      hacc[1][1] = __builtin_amdgcn_mfma_f32_16x16x32_bf16(af1, bf1, hacc[1][1], 0, 0, 0);
    }
    float b10 = B1[ks * 128 + wn * 32 + l15];
    float b11 = B1[ks * 128 + wn * 32 + 16 + l15];
    __syncthreads();  // prior slab's phase-2 reads of Hl done
#pragma unroll
    for (int i = 0; i < 2; i++)
#pragma unroll
      for (int j = 0; j < 2; j++) {
        float bv = j ? b11 : b10;
#pragma unroll
        for (int r = 0; r < 4; r++) {
          float c = hacc[i][j][r] + bv;
          c = 0.5f * c * (1.f + erff(c * 0.70710678118654752f));
          Hl[wm + i * 16 + l4 * 4 + r][wn * 32 + j * 16 + l15] = f2bf(c);
        }
      }
    __syncthreads();
    // ---- phase 2: acc += Hl @ W2 slab (B frags coalesced from L2) ----
    const unsigned short* w2fb = W2F + ((size_t)(ks * 96 + wn * 6)) * 512 + lane * 8;
#pragma unroll
    for (int kk = 0; kk < 4; kk++) {
      short8 af20 = *(const short8*)&Hl[wm + l15][kk * 32 + l4 * 8];
      short8 af21 = *(const short8*)&Hl[wm + 16 + l15][kk * 32 + l4 * 8];
#pragma unroll
      for (int j = 0; j < 6; j++) {
        short8 bf2 = *(const short8*)(w2fb + kk * 12288 + j * 512);
        acc[0][j] = __builtin_amdgcn_mfma_f32_16x16x32_bf16(af20, bf2, acc[0][j], 0, 0, 0);
        acc[1][j] = __builtin_amdgcn_mfma_f32_16x16x32_bf16(af21, bf2, acc[1][j], 0, 0, 0);
      }
    }
  }
  // ---- epilogue: + b2 + residual ----
#pragma unroll
  for (int i = 0; i < 2; i++)
#pragma unroll
    for (int j = 0; j < 6; j++) {
      int n = wn * 96 + j * 16 + l15;
      float bv = B2[n];
#pragma unroll
      for (int r = 0; r < 4; r++) {
        int m = m0 + wm + i * 16 + l4 * 4 + r;
        OUT[(size_t)m * 384 + n] = acc[i][j][r] + bv + X2[(size_t)m * 384 + n];
      }
    }
}

// ---------------- MFMA window attention: 1 wave per (window, head) ----------------
__global__ __launch_bounds__(64) void attn_mfma(
    const __hip_bfloat16* __restrict__ qkv, const __hip_bfloat16* __restrict__ qkv_pad,
    const float* __restrict__ Bexp, __hip_bfloat16* __restrict__ aw) {
  int h = blockIdx.x % NHEAD;
  int w = blockIdx.x / NHEAD;
  int b = w / 25, wi = w % 25;
  int wh = wi / 5, wv = wi % 5;

  __shared__ unsigned short Q[64][40];
  __shared__ unsigned short K[64][40];
  __shared__ unsigned short Vt[32][72];
  __shared__ unsigned short P[64][72];

  int lane = threadIdx.x;
  int l15 = lane & 15, l4 = lane >> 4;

  {
    int t = lane;
    uint4 z = {0, 0, 0, 0};
    uint4 qv[4], kv[4];
    union { uint4 u[4]; unsigned short s[32]; } vu;
    bool use = t < 49;
    const unsigned short* src = (const unsigned short*)qkv_pad + h * 96;
    if (use) {
      int hh = wh * 7 + t / 7, ww = wv * 7 + t % 7;
      if (hh < 32 && ww < 32)
        src = (const unsigned short*)qkv + (size_t)(b * 1024 + hh * 32 + ww) * QKVC + h * 96;
    }
#pragma unroll
    for (int c = 0; c < 4; c++) {
      qv[c]   = use ? *(const uint4*)(src + c * 8)      : z;
      kv[c]   = use ? *(const uint4*)(src + 32 + c * 8) : z;
      vu.u[c] = use ? *(const uint4*)(src + 64 + c * 8) : z;
    }
#pragma unroll
    for (int c = 0; c < 4; c++) {
      *(uint4*)&Q[t][c * 8] = qv[c];
      *(uint4*)&K[t][c * 8] = kv[c];
    }
#pragma unroll
    for (int d = 0; d < 32; d++) Vt[d][t] = vu.s[d];
  }
  __syncthreads();

  f32x4 acc[4][4] = {};
  {
    short8 aq[4], bk[4];
#pragma unroll
    for (int i = 0; i < 4; i++) aq[i] = *(const short8*)&Q[i * 16 + l15][l4 * 8];
#pragma unroll
    for (int j = 0; j < 4; j++) bk[j] = *(const short8*)&K[j * 16 + l15][l4 * 8];
#pragma unroll
    for (int i = 0; i < 4; i++)
#pragma unroll
      for (int j = 0; j < 4; j++)
        acc[i][j] = __builtin_amdgcn_mfma_f32_16x16x32_bf16(aq[i], bk[j], acc[i][j], 0, 0, 0);
  }

  const float* Bh = Bexp + h * 4096;
  float rinv_[4][4];
#pragma unroll
  for (int i = 0; i < 4; i++) {
    float s[4][4];
#pragma unroll
    for (int j = 0; j < 4; j++)
#pragma unroll
      for (int r = 0; r < 4; r++) {
        int n = i * 16 + l4 * 4 + r, m = j * 16 + l15;
        s[j][r] = acc[i][j][r] * SCALE + Bh[n * 64 + m];
      }
#pragma unroll
    for (int r = 0; r < 4; r++) {
      float mx = fmaxf(fmaxf(s[0][r], s[1][r]), fmaxf(s[2][r], s[3][r]));
#pragma unroll
      for (int o = 1; o < 16; o <<= 1) mx = fmaxf(mx, __shfl_xor(mx, o));
      float p[4], sm = 0.f;
#pragma unroll
      for (int j = 0; j < 4; j++) { p[j] = __expf(s[j][r] - mx); sm += p[j]; }
#pragma unroll
      for (int o = 1; o < 16; o <<= 1) sm += __shfl_xor(sm, o);
      rinv_[i][r] = 1.f / sm;
      int n = i * 16 + l4 * 4 + r;
#pragma unroll
      for (int j = 0; j < 4; j++) P[n][j * 16 + l15] = f2bf(p[j]);
    }
  }
  __syncthreads();

  f32x4 o[4][2] = {};
#pragma unroll
  for (int ks = 0; ks < 2; ks++) {
    short8 pa[4], vb[2];
#pragma unroll
    for (int i = 0; i < 4; i++) pa[i] = *(const short8*)&P[i * 16 + l15][ks * 32 + l4 * 8];
#pragma unroll
    for (int j = 0; j < 2; j++) vb[j] = *(const short8*)&Vt[j * 16 + l15][ks * 32 + l4 * 8];
#pragma unroll
    for (int i = 0; i < 4; i++)
#pragma unroll
      for (int j = 0; j < 2; j++)
        o[i][j] = __builtin_amdgcn_mfma_f32_16x16x32_bf16(pa[i], vb[j], o[i][j], 0, 0, 0);
  }

#pragma unroll
  for (int i = 0; i < 4; i++)
#pragma unroll
    for (int r = 0; r < 4; r++) {
      int n = i * 16 + l4 * 4 + r;
      if (n < 49) {
        int hh = wh * 7 + n / 7, ww = wv * 7 + n % 7;
        if (hh < 32 && ww < 32) {
          __hip_bfloat16* dst = aw + (size_t)(b * 1024 + hh * 32 + ww) * CDIM + h * 32;
          float ri = rinv_[i][r];
#pragma unroll
          for (int j = 0; j < 2; j++)
            dst[j * 16 + l15] = __float2bfloat16(o[i][j][r] * ri);
        }
      }
    }
}

// ------- fused depthwise 3x3 conv + BN + LN2: block = (b, x, y-half), thread = channel -------
__global__ __launch_bounds__(384) void conv_bn_ln_kernel(
    const float* __restrict__ X, const float* __restrict__ W9,
    const float* __restrict__ g, const float* __restrict__ bb,
    const float* __restrict__ mm, const float* __restrict__ vv,
    const float* __restrict__ lg, const float* __restrict__ lb,
    float* __restrict__ X2, __hip_bfloat16* __restrict__ XN) {
  int nwg = gridDim.x;
  int id = blockIdx.x;
  int nid = (id & 7) * (nwg >> 3) + (id >> 3);
  int yh = nid & 1;
  int x = (nid >> 1) & 31;
  int b = nid >> 6;
  int c = threadIdx.x;

  float w[9];
#pragma unroll
  for (int i = 0; i < 9; i++) w[i] = W9[c * 9 + i];
  float bnsc = rsqrtf(vv[c] + 1e-5f) * g[c];
  float bnsh = bb[c] - mm[c] * bnsc;
  float lgc = lg[c], lbc = lb[c];

  bool xm = x > 0, xp = x < 31;
  const float* colbase = X + ((size_t)(b * 1024 + x)) * CDIM + c;

  __shared__ float part[2][6][2];
  int wv = threadIdx.x >> 6, ln = threadIdx.x & 63;

  float w0[3], w1[3], w2[3];
  int y0 = yh * 16;
  if (y0 == 0) {
    w0[0] = w0[1] = w0[2] = 0.f;
  } else {
    const float* p = colbase + (size_t)(y0 - 1) * 32 * CDIM;
    w0[0] = xm ? p[-CDIM] : 0.f; w0[1] = p[0]; w0[2] = xp ? p[CDIM] : 0.f;
  }
  {
    const float* p = colbase + (size_t)y0 * 32 * CDIM;
    w1[0] = xm ? p[-CDIM] : 0.f; w1[1] = p[0]; w1[2] = xp ? p[CDIM] : 0.f;
  }

  for (int y = y0; y < y0 + 16; y++) {
    if (y + 1 < 32) {
      const float* p = colbase + (size_t)(y + 1) * 32 * CDIM;
      w2[0] = xm ? p[-CDIM] : 0.f; w2[1] = p[0]; w2[2] = xp ? p[CDIM] : 0.f;
    } else {
      w2[0] = w2[1] = w2[2] = 0.f;
    }
    float acc = w0[0] * w[0] + w0[1] * w[1] + w0[2] * w[2]
              + w1[0] * w[3] + w1[1] * w[4] + w1[2] * w[5]
              + w2[0] * w[6] + w2[1] * w[7] + w2[2] * w[8];
    float r = acc * bnsc + bnsh;
    size_t tok = (size_t)(b * 1024 + y * 32 + x);
    X2[tok * CDIM + c] = r;

    float s1 = r, s2 = r * r;
#pragma unroll
    for (int o = 32; o > 0; o >>= 1) { s1 += __shfl_xor(s1, o); s2 += __shfl_xor(s2, o); }
    int pb = y & 1;
    if (ln == 0) { part[pb][wv][0] = s1; part[pb][wv][1] = s2; }
    __syncthreads();
    float ts1 = 0.f, ts2 = 0.f;
#pragma unroll
    for (int i = 0; i < 6; i++) { ts1 += part[pb][i][0]; ts2 += part[pb][i][1]; }
    float mean = ts1 * (1.f / 384.f);
    float var = ts2 * (1.f / 384.f) - mean * mean;
    float rstd = rsqrtf(var + 1e-5f);
    XN[tok * CDIM + c] = __float2bfloat16((r - mean) * rstd * lgc + lbc);

    w0[0] = w1[0]; w0[1] = w1[1]; w0[2] = w1[2];
    w1[0] = w2[0]; w1[1] = w2[1]; w1[2] = w2[2];
  }
}

extern "C" void kernel_launch(void* const* d_in, const int* in_sizes, int n_in,
                              void* d_out, int out_size, void* d_ws, size_t ws_size,
                              hipStream_t stream) {
  const float* x      = (const float*)d_in[0];
  const float* ln1_g  = (const float*)d_in[1];
  const float* ln1_b  = (const float*)d_in[2];
  const float* qkv_w  = (const float*)d_in[3];
  const float* qkv_b  = (const float*)d_in[4];
  const float* proj_w = (const float*)d_in[5];
  const float* proj_b = (const float*)d_in[6];
  const float* att_b  = (const float*)d_in[7];
  const float* conv_w = (const float*)d_in[8];
  const float* bn_g   = (const float*)d_in[9];
  const float* bn_b   = (const float*)d_in[10];
  const float* bn_m   = (const float*)d_in[11];
  const float* bn_v   = (const float*)d_in[12];
  const float* ln2_g  = (const float*)d_in[13];
  const float* ln2_b  = (const float*)d_in[14];
  const float* fc1_w  = (const float*)d_in[15];
  const float* fc1_b  = (const float*)d_in[16];
  const float* fc2_w  = (const float*)d_in[17];
  const float* fc2_b  = (const float*)d_in[18];
  const int* bias_idxs = (const int*)d_in[19];
  int n_off = in_sizes[7] / NHEAD;
  float* out = (float*)d_out;

  char* ws = (char*)d_ws;
  size_t off = 0;
  __hip_bfloat16* qkv_pad = (__hip_bfloat16*)(ws + off); off += QKVC * 2;
  off = (off + 255) & ~(size_t)255;
  float* Bexp = (float*)(ws + off); off += (size_t)NHEAD * 4096 * 4;
  __hip_bfloat16* wqkvT = (__hip_bfloat16*)(ws + off); off += (size_t)QKVC * CDIM * 2;
  __hip_bfloat16* wprojT = (__hip_bfloat16*)(ws + off); off += (size_t)CDIM * CDIM * 2;
  unsigned short* w1f = (unsigned short*)(ws + off); off += (size_t)MLPH * CDIM * 2;
  unsigned short* w2f = (unsigned short*)(ws + off); off += (size_t)CDIM * MLPH * 2;
  size_t HDR = (off + 255) & ~(size_t)255;

  // per-token chunk scratch: xn bf16(768) + qkv bf16(2304) + awb bf16(768)
  //                        + x1 f32(1536) + x2 f32(1536) = 6912 B
  const size_t PER_TOK = 6912;
  int Bc = 64;
  while (Bc > 1 && HDR + (size_t)Bc * 1024 * PER_TOK > ws_size) Bc >>= 1;
  size_t Tc = (size_t)Bc * 1024;

  off = HDR;
  __hip_bfloat16* xn = (__hip_bfloat16*)(ws + off); off += Tc * CDIM * 2;
  __hip_bfloat16* qkv = (__hip_bfloat16*)(ws + off); off += Tc * QKVC * 2;
  __hip_bfloat16* awb = (__hip_bfloat16*)(ws + off); off += Tc * CDIM * 2;
  float* x1 = (float*)(ws + off); off += Tc * CDIM * 4;
  float* x2 = (float*)(ws + off); off += Tc * CDIM * 4;

  pad_qkv_kernel<<<dim3(5), dim3(256), 0, stream>>>(ln1_b, qkv_w, qkv_b, qkv_pad);
  expand_bias<<<dim3(NHEAD), dim3(256), 0, stream>>>(att_b, bias_idxs, Bexp, n_off);
  wt_convert<<<dim3(QKVC / 32, CDIM / 32), dim3(32, 8), 0, stream>>>(qkv_w, wqkvT, CDIM, QKVC);
  wt_convert<<<dim3(CDIM / 32, CDIM / 32), dim3(32, 8), 0, stream>>>(proj_w, wprojT, CDIM, CDIM);
  wfrag1<<<dim3(1152), dim3(64), 0, stream>>>(fc1_w, w1f);
  wfrag2<<<dim3(1152), dim3(64), 0, stream>>>(fc2_w, w2f);

  for (int b0 = 0; b0 < 64; b0 += Bc) {
    const float* xa = x + (size_t)b0 * 1024 * CDIM;
    float* outa = out + (size_t)b0 * 1024 * CDIM;
    int M = (int)Tc;

    ln_kernel<<<dim3(M / 4), dim3(256), 0, stream>>>(xa, ln1_g, ln1_b, xn, M);
    gemm_mfma<0, 0, 1><<<dim3(QKVC / 64, M / 128), dim3(256), 0, stream>>>(
        xn, wqkvT, qkv_b, nullptr, qkv, M, QKVC, CDIM);
    attn_mfma<<<dim3(Bc * 25 * NHEAD), dim3(64), 0, stream>>>(qkv, qkv_pad, Bexp, awb);
    gemm_mfma<0, 1, 0><<<dim3(CDIM / 64, M / 128), dim3(256), 0, stream>>>(
        awb, wprojT, proj_b, xa, x1, M, CDIM, CDIM);
    conv_bn_ln_kernel<<<dim3(Bc * 64), dim3(384), 0, stream>>>(
        x1, conv_w, bn_g, bn_b, bn_m, bn_v, ln2_g, ln2_b, x2, xn);
    mlp_fused<<<dim3(M / 64), dim3(512), 0, stream>>>(
        xn, w1f, fc1_b, w2f, fc2_b, x2, outa);
  }
}

// Round 8
// 811.028 us; speedup vs baseline: 1.9737x; 1.0185x over previous
//
#include <hip/hip_runtime.h>
#include <hip/hip_bf16.h>
#include <math.h>

#define NHEAD 12
#define CDIM 384
#define QKVC 1152
#define MLPH 1536
#define SCALE 0.17677669529663687f  // 32^-0.5

typedef __attribute__((ext_vector_type(8))) short short8;
typedef __attribute__((ext_vector_type(4))) float f32x4;

static __device__ __forceinline__ unsigned short f2bf(float f) {
  union { __hip_bfloat16 b; unsigned short u; } c;
  c.b = __float2bfloat16(f);
  return c.u;
}

// ---------------- LN (wave per token, C=384) -> bf16 out ----------------
__global__ void ln_kernel(const float* __restrict__ X, const float* __restrict__ g,
                          const float* __restrict__ b, __hip_bfloat16* __restrict__ Y, int T) {
  int wid = (blockIdx.x * blockDim.x + threadIdx.x) >> 6;
  int lane = threadIdx.x & 63;
  if (wid >= T) return;
  const float* x = X + (size_t)wid * CDIM;
  float vals[6];
  float s = 0.f;
#pragma unroll
  for (int i = 0; i < 6; i++) { vals[i] = x[lane + i * 64]; s += vals[i]; }
#pragma unroll
  for (int o = 32; o > 0; o >>= 1) s += __shfl_xor(s, o);
  float m = s * (1.f / 384.f);
  float vs = 0.f;
#pragma unroll
  for (int i = 0; i < 6; i++) { float d = vals[i] - m; vs += d * d; }
#pragma unroll
  for (int o = 32; o > 0; o >>= 1) vs += __shfl_xor(vs, o);
  float rs = rsqrtf(vs * (1.f / 384.f) + 1e-5f);
  __hip_bfloat16* y = Y + (size_t)wid * CDIM;
#pragma unroll
  for (int i = 0; i < 6; i++) {
    int c = lane + i * 64;
    y[c] = __float2bfloat16((vals[i] - m) * rs * g[c] + b[c]);
  }
}

// ------------- qkv of a padded (zero) token: ln1_b @ qkv_w + qkv_b -> bf16 -------------
__global__ void pad_qkv_kernel(const float* __restrict__ lb, const float* __restrict__ Wq,
                               const float* __restrict__ bq, __hip_bfloat16* __restrict__ outp) {
  int j = blockIdx.x * blockDim.x + threadIdx.x;
  if (j >= QKVC) return;
  float s = bq[j];
  for (int c = 0; c < CDIM; c++) s += lb[c] * Wq[(size_t)c * QKVC + j];
  outp[j] = __float2bfloat16(s);
}

// ------------- expand relative-position bias to padded [12][64][64] f32 -------------
__global__ void expand_bias(const float* __restrict__ biases, const int* __restrict__ bidx,
                            float* __restrict__ Bexp, int n_off) {
  int h = blockIdx.x;
  for (int e = threadIdx.x; e < 4096; e += 256) {
    int n = e >> 6, m = e & 63;
    float v;
    if (m >= 49) v = -1e30f;
    else if (n >= 49) v = 0.f;
    else v = biases[h * n_off + bidx[n * 49 + m]];
    Bexp[h * 4096 + e] = v;
  }
}

// ---------------- weight transpose + f32->bf16 convert: W[K][N] -> Wt[N][K] ----------------
__global__ void wt_convert(const float* __restrict__ W, __hip_bfloat16* __restrict__ Wt,
                           int K, int N) {
  __shared__ float t[32][33];
  int n0 = blockIdx.x * 32, k0 = blockIdx.y * 32;
  int tx = threadIdx.x, ty = threadIdx.y;  // 32 x 8
#pragma unroll
  for (int i = 0; i < 4; i++) t[ty + i * 8][tx] = W[(size_t)(k0 + ty + i * 8) * N + n0 + tx];
  __syncthreads();
#pragma unroll
  for (int i = 0; i < 4; i++)
    Wt[(size_t)(n0 + ty + i * 8) * K + k0 + tx] = __float2bfloat16(t[tx][ty + i * 8]);
}

// -------- pack fc1_w [384][1536] into phase-1 MFMA fragment order (1m x 8n waves) --------
// frag f = ks*96 + kk*8 + wn ; lane holds B[n][k]:
// n = ks*128 + wn*16 + (lane&15), k = kk*32 + (lane>>4)*8 + j
__global__ void wfrag1(const float* __restrict__ W, unsigned short* __restrict__ WF) {
  int f = blockIdx.x;
  int lane = threadIdx.x;
  int wn = f & 7, kk = (f >> 3) % 12, ks = f / 96;
  int n = ks * 128 + wn * 16 + (lane & 15);
  int k = kk * 32 + (lane >> 4) * 8;
  unsigned short* dst = WF + ((size_t)f * 64 + lane) * 8;
#pragma unroll
  for (int j = 0; j < 8; j++) dst[j] = f2bf(W[(size_t)(k + j) * MLPH + n]);
}

// -------- pack fc2_w [1536][384] into phase-2 MFMA fragment order (1m x 8n waves) --------
// frag f = ks*96 + kk*24 + wn*3 + j ; lane holds B[n][k]:
// n = wn*48 + j*16 + (lane&15), k = ks*128 + kk*32 + (lane>>4)*8 + jj
__global__ void wfrag2(const float* __restrict__ W, unsigned short* __restrict__ WF) {
  int f = blockIdx.x;
  int lane = threadIdx.x;
  int j = f % 3, wn = (f / 3) & 7, kk = (f / 24) & 3, ks = f / 96;
  int n = wn * 48 + j * 16 + (lane & 15);
  int k = ks * 128 + kk * 32 + (lane >> 4) * 8;
  unsigned short* dst = WF + ((size_t)f * 64 + lane) * 8;
#pragma unroll
  for (int jj = 0; jj < 8; jj++) dst[jj] = f2bf(W[(size_t)(k + jj) * CDIM + n]);
}

// ---------------- bf16 MFMA GEMM (R4 form): C = A @ Bt^T + bias (+res) ----------------
template <int GELU, int HAS_RES, int OUT_BF16>
__global__ __launch_bounds__(256) void gemm_mfma(
    const __hip_bfloat16* __restrict__ A, const __hip_bfloat16* __restrict__ Bt,
    const float* __restrict__ bias, const float* __restrict__ res,
    void* __restrict__ Cout, int M, int N, int K) {
  __shared__ unsigned short Al[128][72];
  __shared__ unsigned short Bl[64][72];
  int tid = threadIdx.x;
  int m0 = blockIdx.y * 128, n0 = blockIdx.x * 64;
  int wave = tid >> 6, lane = tid & 63;
  int wm = (wave >> 1) * 64, wn = (wave & 1) * 32;
  int l15 = lane & 15, l4 = lane >> 4;

  int am = tid >> 1, ak = (tid & 1) * 32;
  int bn = tid >> 2, bk = (tid & 3) * 16;
  const __hip_bfloat16* Ag = A + (size_t)(m0 + am) * K + ak;
  const __hip_bfloat16* Bg = Bt + (size_t)(n0 + bn) * K + bk;

  f32x4 acc[4][2] = {};

  for (int kt = 0; kt < K; kt += 64) {
    uint4 av0 = *(const uint4*)(Ag + kt);
    uint4 av1 = *(const uint4*)(Ag + kt + 8);
    uint4 av2 = *(const uint4*)(Ag + kt + 16);
    uint4 av3 = *(const uint4*)(Ag + kt + 24);
    uint4 bv0 = *(const uint4*)(Bg + kt);
    uint4 bv1 = *(const uint4*)(Bg + kt + 8);
    __syncthreads();
    *(uint4*)&Al[am][ak]      = av0;
    *(uint4*)&Al[am][ak + 8]  = av1;
    *(uint4*)&Al[am][ak + 16] = av2;
    *(uint4*)&Al[am][ak + 24] = av3;
    *(uint4*)&Bl[bn][bk]      = bv0;
    *(uint4*)&Bl[bn][bk + 8]  = bv1;
    __syncthreads();
#pragma unroll
    for (int kk = 0; kk < 64; kk += 32) {
      short8 af[4], bfr[2];
#pragma unroll
      for (int i = 0; i < 4; i++)
        af[i] = *(const short8*)&Al[wm + i * 16 + l15][kk + l4 * 8];
#pragma unroll
      for (int j = 0; j < 2; j++)
        bfr[j] = *(const short8*)&Bl[wn + j * 16 + l15][kk + l4 * 8];
#pragma unroll
      for (int i = 0; i < 4; i++)
#pragma unroll
        for (int j = 0; j < 2; j++)
          acc[i][j] = __builtin_amdgcn_mfma_f32_16x16x32_bf16(af[i], bfr[j], acc[i][j], 0, 0, 0);
    }
  }

#pragma unroll
  for (int i = 0; i < 4; i++) {
#pragma unroll
    for (int j = 0; j < 2; j++) {
      int n = n0 + wn + j * 16 + l15;
      float bv = bias[n];
#pragma unroll
      for (int r = 0; r < 4; r++) {
        int m = m0 + wm + i * 16 + l4 * 4 + r;
        float c = acc[i][j][r] + bv;
        if (GELU) c = 0.5f * c * (1.f + erff(c * 0.70710678118654752f));
        if (HAS_RES) c += res[(size_t)m * N + n];
        if (OUT_BF16)
          ((__hip_bfloat16*)Cout)[(size_t)m * N + n] = __float2bfloat16(c);
        else
          ((float*)Cout)[(size_t)m * N + n] = c;
      }
    }
  }
}

// ---------------- fused MLP: OUT = gelu(XN @ W1 + b1) @ W2 + b2 + X2 ----------------
// 8 waves, 1m x 8n: each wave covers all 64 rows and a disjoint 1/8 of n-cols ->
// ZERO weight-fragment duplication across waves (halves L2 traffic vs 2m x 4n).
// LDS pitches 388/132 shorts: row stride = 2 words mod 32 -> conflict-free b128.
__global__ __launch_bounds__(512) void mlp_fused(
    const __hip_bfloat16* __restrict__ XN, const unsigned short* __restrict__ W1F,
    const float* __restrict__ B1, const unsigned short* __restrict__ W2F,
    const float* __restrict__ B2, const float* __restrict__ X2,
    float* __restrict__ OUT) {
  __shared__ unsigned short XNl[64][388];
  __shared__ unsigned short Hl[64][132];
  int tid = threadIdx.x;
  int m0 = blockIdx.x * 64;
  int wave = tid >> 6, lane = tid & 63;
  int wn = wave;  // 8 n-groups
  int l15 = lane & 15, l4 = lane >> 4;

  {  // stage A panel 64x384 bf16, fully coalesced uint4 order
#pragma unroll
    for (int i = 0; i < 6; i++) {
      int u = tid + i * 512;
      int r = u / 48, col = (u % 48) * 8;
      *(uint4*)&XNl[r][col] =
          *(const uint4*)((const unsigned short*)XN + (size_t)(m0 + r) * 384 + col);
    }
  }

  f32x4 acc[4][3] = {};
  __syncthreads();

  for (int ks = 0; ks < 12; ks++) {
    // ---- phase 1: hacc = XN_panel @ W1 slab (wave owns 16 of 128 h-cols) ----
    f32x4 hacc[4] = {};
    const unsigned short* w1fb = W1F + ((size_t)(ks * 96 + wn)) * 512 + lane * 8;
#pragma unroll
    for (int kk = 0; kk < 12; kk++) {
      short8 bf0 = *(const short8*)(w1fb + kk * 4096);
#pragma unroll
      for (int i = 0; i < 4; i++) {
        short8 af = *(const short8*)&XNl[i * 16 + l15][kk * 32 + l4 * 8];
        hacc[i] = __builtin_amdgcn_mfma_f32_16x16x32_bf16(af, bf0, hacc[i], 0, 0, 0);
      }
    }
    float b1v = B1[ks * 128 + wn * 16 + l15];
    __syncthreads();  // prior slab's phase-2 reads of Hl done
#pragma unroll
    for (int i = 0; i < 4; i++)
#pragma unroll
      for (int r = 0; r < 4; r++) {
        float c = hacc[i][r] + b1v;
        c = 0.5f * c * (1.f + erff(c * 0.70710678118654752f));
        Hl[i * 16 + l4 * 4 + r][wn * 16 + l15] = f2bf(c);
      }
    __syncthreads();
    // ---- phase 2: acc += Hl @ W2 slab (wave owns 48 of 384 out-cols) ----
    const unsigned short* w2fb = W2F + ((size_t)(ks * 96 + wn * 3)) * 512 + lane * 8;
#pragma unroll
    for (int kk = 0; kk < 4; kk++) {
      short8 af2[4];
#pragma unroll
      for (int i = 0; i < 4; i++)
        af2[i] = *(const short8*)&Hl[i * 16 + l15][kk * 32 + l4 * 8];
#pragma unroll
      for (int j = 0; j < 3; j++) {
        short8 bf2 = *(const short8*)(w2fb + kk * 12288 + j * 512);
#pragma unroll
        for (int i = 0; i < 4; i++)
          acc[i][j] = __builtin_amdgcn_mfma_f32_16x16x32_bf16(af2[i], bf2, acc[i][j], 0, 0, 0);
      }
    }
  }
  // ---- epilogue: + b2 + residual ----
#pragma unroll
  for (int j = 0; j < 3; j++) {
    int n = wn * 48 + j * 16 + l15;
    float bv = B2[n];
#pragma unroll
    for (int i = 0; i < 4; i++)
#pragma unroll
      for (int r = 0; r < 4; r++) {
        int m = m0 + i * 16 + l4 * 4 + r;
        OUT[(size_t)m * 384 + n] = acc[i][j][r] + bv + X2[(size_t)m * 384 + n];
      }
  }
}

// ---------------- MFMA window attention: 1 wave per (window, head) ----------------
__global__ __launch_bounds__(64) void attn_mfma(
    const __hip_bfloat16* __restrict__ qkv, const __hip_bfloat16* __restrict__ qkv_pad,
    const float* __restrict__ Bexp, __hip_bfloat16* __restrict__ aw) {
  int h = blockIdx.x % NHEAD;
  int w = blockIdx.x / NHEAD;
  int b = w / 25, wi = w % 25;
  int wh = wi / 5, wv = wi % 5;

  __shared__ unsigned short Q[64][40];
  __shared__ unsigned short K[64][40];
  __shared__ unsigned short Vt[32][72];
  __shared__ unsigned short P[64][72];

  int lane = threadIdx.x;
  int l15 = lane & 15, l4 = lane >> 4;

  {
    int t = lane;
    uint4 z = {0, 0, 0, 0};
    uint4 qv[4], kv[4];
    union { uint4 u[4]; unsigned short s[32]; } vu;
    bool use = t < 49;
    const unsigned short* src = (const unsigned short*)qkv_pad + h * 96;
    if (use) {
      int hh = wh * 7 + t / 7, ww = wv * 7 + t % 7;
      if (hh < 32 && ww < 32)
        src = (const unsigned short*)qkv + (size_t)(b * 1024 + hh * 32 + ww) * QKVC + h * 96;
    }
#pragma unroll
    for (int c = 0; c < 4; c++) {
      qv[c]   = use ? *(const uint4*)(src + c * 8)      : z;
      kv[c]   = use ? *(const uint4*)(src + 32 + c * 8) : z;
      vu.u[c] = use ? *(const uint4*)(src + 64 + c * 8) : z;
    }
#pragma unroll
    for (int c = 0; c < 4; c++) {
      *(uint4*)&Q[t][c * 8] = qv[c];
      *(uint4*)&K[t][c * 8] = kv[c];
    }
#pragma unroll
    for (int d = 0; d < 32; d++) Vt[d][t] = vu.s[d];
  }
  __syncthreads();

  f32x4 acc[4][4] = {};
  {
    short8 aq[4], bk[4];
#pragma unroll
    for (int i = 0; i < 4; i++) aq[i] = *(const short8*)&Q[i * 16 + l15][l4 * 8];
#pragma unroll
    for (int j = 0; j < 4; j++) bk[j] = *(const short8*)&K[j * 16 + l15][l4 * 8];
#pragma unroll
    for (int i = 0; i < 4; i++)
#pragma unroll
      for (int j = 0; j < 4; j++)
        acc[i][j] = __builtin_amdgcn_mfma_f32_16x16x32_bf16(aq[i], bk[j], acc[i][j], 0, 0, 0);
  }

  const float* Bh = Bexp + h * 4096;
  float rinv_[4][4];
#pragma unroll
  for (int i = 0; i < 4; i++) {
    float s[4][4];
#pragma unroll
    for (int j = 0; j < 4; j++)
#pragma unroll
      for (int r = 0; r < 4; r++) {
        int n = i * 16 + l4 * 4 + r, m = j * 16 + l15;
        s[j][r] = acc[i][j][r] * SCALE + Bh[n * 64 + m];
      }
#pragma unroll
    for (int r = 0; r < 4; r++) {
      float mx = fmaxf(fmaxf(s[0][r], s[1][r]), fmaxf(s[2][r], s[3][r]));
#pragma unroll
      for (int o = 1; o < 16; o <<= 1) mx = fmaxf(mx, __shfl_xor(mx, o));
      float p[4], sm = 0.f;
#pragma unroll
      for (int j = 0; j < 4; j++) { p[j] = __expf(s[j][r] - mx); sm += p[j]; }
#pragma unroll
      for (int o = 1; o < 16; o <<= 1) sm += __shfl_xor(sm, o);
      rinv_[i][r] = 1.f / sm;
      int n = i * 16 + l4 * 4 + r;
#pragma unroll
      for (int j = 0; j < 4; j++) P[n][j * 16 + l15] = f2bf(p[j]);
    }
  }
  __syncthreads();

  f32x4 o[4][2] = {};
#pragma unroll
  for (int ks = 0; ks < 2; ks++) {
    short8 pa[4], vb[2];
#pragma unroll
    for (int i = 0; i < 4; i++) pa[i] = *(const short8*)&P[i * 16 + l15][ks * 32 + l4 * 8];
#pragma unroll
    for (int j = 0; j < 2; j++) vb[j] = *(const short8*)&Vt[j * 16 + l15][ks * 32 + l4 * 8];
#pragma unroll
    for (int i = 0; i < 4; i++)
#pragma unroll
      for (int j = 0; j < 2; j++)
        o[i][j] = __builtin_amdgcn_mfma_f32_16x16x32_bf16(pa[i], vb[j], o[i][j], 0, 0, 0);
  }

#pragma unroll
  for (int i = 0; i < 4; i++)
#pragma unroll
    for (int r = 0; r < 4; r++) {
      int n = i * 16 + l4 * 4 + r;
      if (n < 49) {
        int hh = wh * 7 + n / 7, ww = wv * 7 + n % 7;
        if (hh < 32 && ww < 32) {
          __hip_bfloat16* dst = aw + (size_t)(b * 1024 + hh * 32 + ww) * CDIM + h * 32;
          float ri = rinv_[i][r];
#pragma unroll
          for (int j = 0; j < 2; j++)
            dst[j * 16 + l15] = __float2bfloat16(o[i][j][r] * ri);
        }
      }
    }
}

// ------- fused depthwise 3x3 conv + BN + LN2: block = (b, x, y-half), thread = channel -------
__global__ __launch_bounds__(384) void conv_bn_ln_kernel(
    const float* __restrict__ X, const float* __restrict__ W9,
    const float* __restrict__ g, const float* __restrict__ bb,
    const float* __restrict__ mm, const float* __restrict__ vv,
    const float* __restrict__ lg, const float* __restrict__ lb,
    float* __restrict__ X2, __hip_bfloat16* __restrict__ XN) {
  int nwg = gridDim.x;
  int id = blockIdx.x;
  int nid = (id & 7) * (nwg >> 3) + (id >> 3);
  int yh = nid & 1;
  int x = (nid >> 1) & 31;
  int b = nid >> 6;
  int c = threadIdx.x;

  float w[9];
#pragma unroll
  for (int i = 0; i < 9; i++) w[i] = W9[c * 9 + i];
  float bnsc = rsqrtf(vv[c] + 1e-5f) * g[c];
  float bnsh = bb[c] - mm[c] * bnsc;
  float lgc = lg[c], lbc = lb[c];

  bool xm = x > 0, xp = x < 31;
  const float* colbase = X + ((size_t)(b * 1024 + x)) * CDIM + c;

  __shared__ float part[2][6][2];
  int wv = threadIdx.x >> 6, ln = threadIdx.x & 63;

  float w0[3], w1[3], w2[3];
  int y0 = yh * 16;
  if (y0 == 0) {
    w0[0] = w0[1] = w0[2] = 0.f;
  } else {
    const float* p = colbase + (size_t)(y0 - 1) * 32 * CDIM;
    w0[0] = xm ? p[-CDIM] : 0.f; w0[1] = p[0]; w0[2] = xp ? p[CDIM] : 0.f;
  }
  {
    const float* p = colbase + (size_t)y0 * 32 * CDIM;
    w1[0] = xm ? p[-CDIM] : 0.f; w1[1] = p[0]; w1[2] = xp ? p[CDIM] : 0.f;
  }

  for (int y = y0; y < y0 + 16; y++) {
    if (y + 1 < 32) {
      const float* p = colbase + (size_t)(y + 1) * 32 * CDIM;
      w2[0] = xm ? p[-CDIM] : 0.f; w2[1] = p[0]; w2[2] = xp ? p[CDIM] : 0.f;
    } else {
      w2[0] = w2[1] = w2[2] = 0.f;
    }
    float acc = w0[0] * w[0] + w0[1] * w[1] + w0[2] * w[2]
              + w1[0] * w[3] + w1[1] * w[4] + w1[2] * w[5]
              + w2[0] * w[6] + w2[1] * w[7] + w2[2] * w[8];
    float r = acc * bnsc + bnsh;
    size_t tok = (size_t)(b * 1024 + y * 32 + x);
    X2[tok * CDIM + c] = r;

    float s1 = r, s2 = r * r;
#pragma unroll
    for (int o = 32; o > 0; o >>= 1) { s1 += __shfl_xor(s1, o); s2 += __shfl_xor(s2, o); }
    int pb = y & 1;
    if (ln == 0) { part[pb][wv][0] = s1; part[pb][wv][1] = s2; }
    __syncthreads();
    float ts1 = 0.f, ts2 = 0.f;
#pragma unroll
    for (int i = 0; i < 6; i++) { ts1 += part[pb][i][0]; ts2 += part[pb][i][1]; }
    float mean = ts1 * (1.f / 384.f);
    float var = ts2 * (1.f / 384.f) - mean * mean;
    float rstd = rsqrtf(var + 1e-5f);
    XN[tok * CDIM + c] = __float2bfloat16((r - mean) * rstd * lgc + lbc);

    w0[0] = w1[0]; w0[1] = w1[1]; w0[2] = w1[2];
    w1[0] = w2[0]; w1[1] = w2[1]; w1[2] = w2[2];
  }
}

extern "C" void kernel_launch(void* const* d_in, const int* in_sizes, int n_in,
                              void* d_out, int out_size, void* d_ws, size_t ws_size,
                              hipStream_t stream) {
  const float* x      = (const float*)d_in[0];
  const float* ln1_g  = (const float*)d_in[1];
  const float* ln1_b  = (const float*)d_in[2];
  const float* qkv_w  = (const float*)d_in[3];
  const float* qkv_b  = (const float*)d_in[4];
  const float* proj_w = (const float*)d_in[5];
  const float* proj_b = (const float*)d_in[6];
  const float* att_b  = (const float*)d_in[7];
  const float* conv_w = (const float*)d_in[8];
  const float* bn_g   = (const float*)d_in[9];
  const float* bn_b   = (const float*)d_in[10];
  const float* bn_m   = (const float*)d_in[11];
  const float* bn_v   = (const float*)d_in[12];
  const float* ln2_g  = (const float*)d_in[13];
  const float* ln2_b  = (const float*)d_in[14];
  const float* fc1_w  = (const float*)d_in[15];
  const float* fc1_b  = (const float*)d_in[16];
  const float* fc2_w  = (const float*)d_in[17];
  const float* fc2_b  = (const float*)d_in[18];
  const int* bias_idxs = (const int*)d_in[19];
  int n_off = in_sizes[7] / NHEAD;
  float* out = (float*)d_out;

  char* ws = (char*)d_ws;
  size_t off = 0;
  __hip_bfloat16* qkv_pad = (__hip_bfloat16*)(ws + off); off += QKVC * 2;
  off = (off + 255) & ~(size_t)255;
  float* Bexp = (float*)(ws + off); off += (size_t)NHEAD * 4096 * 4;
  __hip_bfloat16* wqkvT = (__hip_bfloat16*)(ws + off); off += (size_t)QKVC * CDIM * 2;
  __hip_bfloat16* wprojT = (__hip_bfloat16*)(ws + off); off += (size_t)CDIM * CDIM * 2;
  unsigned short* w1f = (unsigned short*)(ws + off); off += (size_t)MLPH * CDIM * 2;
  unsigned short* w2f = (unsigned short*)(ws + off); off += (size_t)CDIM * MLPH * 2;
  size_t HDR = (off + 255) & ~(size_t)255;

  const size_t PER_TOK = 6912;
  int Bc = 64;
  while (Bc > 1 && HDR + (size_t)Bc * 1024 * PER_TOK > ws_size) Bc >>= 1;
  size_t Tc = (size_t)Bc * 1024;

  off = HDR;
  __hip_bfloat16* xn = (__hip_bfloat16*)(ws + off); off += Tc * CDIM * 2;
  __hip_bfloat16* qkv = (__hip_bfloat16*)(ws + off); off += Tc * QKVC * 2;
  __hip_bfloat16* awb = (__hip_bfloat16*)(ws + off); off += Tc * CDIM * 2;
  float* x1 = (float*)(ws + off); off += Tc * CDIM * 4;
  float* x2 = (float*)(ws + off); off += Tc * CDIM * 4;

  pad_qkv_kernel<<<dim3(5), dim3(256), 0, stream>>>(ln1_b, qkv_w, qkv_b, qkv_pad);
  expand_bias<<<dim3(NHEAD), dim3(256), 0, stream>>>(att_b, bias_idxs, Bexp, n_off);
  wt_convert<<<dim3(QKVC / 32, CDIM / 32), dim3(32, 8), 0, stream>>>(qkv_w, wqkvT, CDIM, QKVC);
  wt_convert<<<dim3(CDIM / 32, CDIM / 32), dim3(32, 8), 0, stream>>>(proj_w, wprojT, CDIM, CDIM);
  wfrag1<<<dim3(1152), dim3(64), 0, stream>>>(fc1_w, w1f);
  wfrag2<<<dim3(1152), dim3(64), 0, stream>>>(fc2_w, w2f);

  for (int b0 = 0; b0 < 64; b0 += Bc) {
    const float* xa = x + (size_t)b0 * 1024 * CDIM;
    float* outa = out + (size_t)b0 * 1024 * CDIM;
    int M = (int)Tc;

    ln_kernel<<<dim3(M / 4), dim3(256), 0, stream>>>(xa, ln1_g, ln1_b, xn, M);
    gemm_mfma<0, 0, 1><<<dim3(QKVC / 64, M / 128), dim3(256), 0, stream>>>(
        xn, wqkvT, qkv_b, nullptr, qkv, M, QKVC, CDIM);
    attn_mfma<<<dim3(Bc * 25 * NHEAD), dim3(64), 0, stream>>>(qkv, qkv_pad, Bexp, awb);
    gemm_mfma<0, 1, 0><<<dim3(CDIM / 64, M / 128), dim3(256), 0, stream>>>(
        awb, wprojT, proj_b, xa, x1, M, CDIM, CDIM);
    conv_bn_ln_kernel<<<dim3(Bc * 64), dim3(384), 0, stream>>>(
        x1, conv_w, bn_g, bn_b, bn_m, bn_v, ln2_g, ln2_b, x2, xn);
    mlp_fused<<<dim3(M / 64), dim3(512), 0, stream>>>(
        xn, w1f, fc1_b, w2f, fc2_b, x2, outa);
  }
}